// Round 1
// baseline (2570.500 us; speedup 1.0000x reference)
//
#include <hip/hip_runtime.h>

#define NUQ 100000
#define NIQ 100000
#define NHN 200000
#define CC 128
#define PDM 64
#define PHM 128
#define EHET 500000
#define EHOM 1000000

// ---------- init: xh = [x_user; x_item] ----------
__global__ void k_init(const float* __restrict__ xu, const float* __restrict__ xi,
                       float* __restrict__ xh) {
  int i = blockIdx.x * 256 + threadIdx.x;
  const int total = NHN * CC;
  if (i < total) {
    const int uc = NUQ * CC;
    xh[i] = (i < uc) ? xu[i] : xi[i - uc];
  }
}

// ---------- in-degree counts for seg_mean (both directions) ----------
__global__ void k_count(const int* __restrict__ eui_dst, const int* __restrict__ eiu_dst,
                        int* __restrict__ cnt) {
  int i = blockIdx.x * 256 + threadIdx.x;
  if (i < EHET) {
    atomicAdd(&cnt[NUQ + eui_dst[i]], 1);          // items
  } else if (i < 2 * EHET) {
    atomicAdd(&cnt[eiu_dst[i - EHET]], 1);         // users
  }
}

// ---------- GIN neighborhood sum over homogeneous edges (layer-invariant) ----------
__global__ void k_agg(const int* __restrict__ hs, const int* __restrict__ hd,
                      const float* __restrict__ pe, float* __restrict__ agg) {
  int gid = blockIdx.x * 256 + threadIdx.x;
  if (gid < EHOM * PDM) {
    int e = gid >> 6, d = gid & 63;
    atomicAdd(&agg[hd[e] * PDM + d], pe[hs[e] * PDM + d]);
  }
}

// ---------- fused GIN MLP: pe_l = relu(h@W1+b1)@W2+b2, h=(1+eps)*PE+agg ----------
__global__ __launch_bounds__(128) void k_gin(
    const float* __restrict__ pe, const float* __restrict__ agg,
    const float* __restrict__ W1, const float* __restrict__ b1,
    const float* __restrict__ W2, const float* __restrict__ b2,
    const float* __restrict__ eps_p, float* __restrict__ out) {
  __shared__ float h[4][PDM];
  __shared__ float hid[4][PHM];
  int row0 = blockIdx.x * 4;
  int t = threadIdx.x;
  float e1 = 1.0f + eps_p[0];
  if (t < PDM) {
#pragma unroll
    for (int r = 0; r < 4; ++r)
      h[r][t] = e1 * pe[(row0 + r) * PDM + t] + agg[(row0 + r) * PDM + t];
  }
  __syncthreads();
  float a0 = b1[t], a1 = a0, a2 = a0, a3 = a0;
  for (int k = 0; k < PDM; ++k) {
    float w = W1[k * PHM + t];
    a0 += h[0][k] * w; a1 += h[1][k] * w; a2 += h[2][k] * w; a3 += h[3][k] * w;
  }
  hid[0][t] = fmaxf(a0, 0.f); hid[1][t] = fmaxf(a1, 0.f);
  hid[2][t] = fmaxf(a2, 0.f); hid[3][t] = fmaxf(a3, 0.f);
  __syncthreads();
  int d = t & 63, rb = t >> 6;
  float o0 = b2[d], o1 = b2[d];
  for (int k = 0; k < PHM; ++k) {
    float w = W2[k * PDM + d];
    o0 += hid[rb][k] * w;
    o1 += hid[rb + 2][k] * w;
  }
  out[(row0 + rb) * PDM + d] = o0;
  out[(row0 + rb + 2) * PDM + d] = o1;
}

// ---------- y = concat(xh, pe_l) @ pe_W + pe_b   (K=192, N=128) ----------
__global__ __launch_bounds__(128) void k_peproj(
    const float* __restrict__ xh, const float* __restrict__ pe_l,
    const float* __restrict__ W, const float* __restrict__ b,
    float* __restrict__ y) {
  __shared__ __align__(16) float Lds[16][CC + PDM];
  int row0 = blockIdx.x * 16;
  int t = threadIdx.x;
#pragma unroll
  for (int r = 0; r < 16; ++r)
    Lds[r][t] = xh[(row0 + r) * CC + t];
  if (t < PDM) {
#pragma unroll
    for (int r = 0; r < 16; ++r)
      Lds[r][CC + t] = pe_l[(row0 + r) * PDM + t];
  }
  __syncthreads();
  float acc[16];
  float bv = b[t];
#pragma unroll
  for (int r = 0; r < 16; ++r) acc[r] = bv;
  for (int k0 = 0; k0 < CC + PDM; k0 += 4) {
    float w0 = W[(k0 + 0) * CC + t], w1 = W[(k0 + 1) * CC + t],
          w2 = W[(k0 + 2) * CC + t], w3 = W[(k0 + 3) * CC + t];
#pragma unroll
    for (int r = 0; r < 16; ++r) {
      float4 h4 = *reinterpret_cast<const float4*>(&Lds[r][k0]);
      acc[r] += h4.x * w0 + h4.y * w1 + h4.z * w2 + h4.w * w3;
    }
  }
#pragma unroll
  for (int r = 0; r < 16; ++r)
    y[(row0 + r) * CC + t] = acc[r];
}

// ---------- seg-sum scatter: msum[dst+dstBase] += y[src+srcBase] ----------
__global__ void k_scatter(const int* __restrict__ src, const int* __restrict__ dst,
                          const float* __restrict__ y, float* __restrict__ msum,
                          int srcBase, int dstBase) {
  int gid = blockIdx.x * 256 + threadIdx.x;
  if (gid < EHET * CC) {
    int e = gid >> 7, c = gid & 127;
    atomicAdd(&msum[(dst[e] + dstBase) * CC + c], y[(src[e] + srcBase) * CC + c]);
  }
}

// ---------- out = (msum/cnt)@Wl + bl + y@Wr, then LayerNorm + ReLU -> xh ----------
__global__ __launch_bounds__(128) void k_sage_ln(
    const float* __restrict__ y, const float* __restrict__ msum, const int* __restrict__ cnt,
    const float* __restrict__ Wl_u, const float* __restrict__ bl_u, const float* __restrict__ Wr_u,
    const float* __restrict__ Wl_i, const float* __restrict__ bl_i, const float* __restrict__ Wr_i,
    const float* __restrict__ g_u, const float* __restrict__ be_u,
    const float* __restrict__ g_i, const float* __restrict__ be_i,
    float* __restrict__ xh) {
  __shared__ __align__(16) float Ms[16][CC];
  __shared__ __align__(16) float Ys[16][CC];
  __shared__ float stat[16][2];
  __shared__ float rinv_s[16];
  int row0 = blockIdx.x * 16;
  int t = threadIdx.x;
  const bool isU = (row0 < NUQ);
  const float* Wl = isU ? Wl_u : Wl_i;
  const float* Wr = isU ? Wr_u : Wr_i;
  const float* bl = isU ? bl_u : bl_i;
  const float* g  = isU ? g_u  : g_i;
  const float* be = isU ? be_u : be_i;
  if (t < 16) rinv_s[t] = 1.0f / fmaxf((float)cnt[row0 + t], 1.0f);
  __syncthreads();
#pragma unroll
  for (int r = 0; r < 16; ++r) {
    Ms[r][t] = msum[(row0 + r) * CC + t] * rinv_s[r];
    Ys[r][t] = y[(row0 + r) * CC + t];
  }
  __syncthreads();
  float acc[16];
  float blv = bl[t];
#pragma unroll
  for (int r = 0; r < 16; ++r) acc[r] = blv;
  for (int k0 = 0; k0 < CC; k0 += 4) {
    float wl0 = Wl[(k0 + 0) * CC + t], wl1 = Wl[(k0 + 1) * CC + t],
          wl2 = Wl[(k0 + 2) * CC + t], wl3 = Wl[(k0 + 3) * CC + t];
    float wr0 = Wr[(k0 + 0) * CC + t], wr1 = Wr[(k0 + 1) * CC + t],
          wr2 = Wr[(k0 + 2) * CC + t], wr3 = Wr[(k0 + 3) * CC + t];
#pragma unroll
    for (int r = 0; r < 16; ++r) {
      float4 m4 = *reinterpret_cast<const float4*>(&Ms[r][k0]);
      float4 y4 = *reinterpret_cast<const float4*>(&Ys[r][k0]);
      acc[r] += m4.x * wl0 + m4.y * wl1 + m4.z * wl2 + m4.w * wl3
              + y4.x * wr0 + y4.y * wr1 + y4.z * wr2 + y4.w * wr3;
    }
  }
  __syncthreads();
#pragma unroll
  for (int r = 0; r < 16; ++r) Ms[r][t] = acc[r];
  __syncthreads();
  int rr = t >> 3, j = t & 7;
  float s = 0.f, sq = 0.f;
#pragma unroll
  for (int i = 0; i < 16; ++i) {
    float v = Ms[rr][j + 8 * i];
    s += v; sq += v * v;
  }
  s += __shfl_xor(s, 1); sq += __shfl_xor(sq, 1);
  s += __shfl_xor(s, 2); sq += __shfl_xor(sq, 2);
  s += __shfl_xor(s, 4); sq += __shfl_xor(sq, 4);
  if (j == 0) {
    float mu = s * (1.0f / CC);
    float var = sq * (1.0f / CC) - mu * mu;
    stat[rr][0] = mu;
    stat[rr][1] = rsqrtf(var + 1e-5f);
  }
  __syncthreads();
  float gv = g[t], bv = be[t];
#pragma unroll
  for (int r = 0; r < 16; ++r) {
    float v = (Ms[r][t] - stat[r][0]) * stat[r][1] * gv + bv;
    xh[(row0 + r) * CC + t] = fmaxf(v, 0.0f);
  }
}

extern "C" void kernel_launch(void* const* d_in, const int* in_sizes, int n_in,
                              void* d_out, int out_size, void* d_ws, size_t ws_size,
                              hipStream_t stream) {
  const float* x_user = (const float*)d_in[0];
  const float* x_item = (const float*)d_in[1];
  const float* PE     = (const float*)d_in[2];
  const float* sui_Wl = (const float*)d_in[3];
  const float* sui_bl = (const float*)d_in[4];
  const float* sui_Wr = (const float*)d_in[5];
  const float* siu_Wl = (const float*)d_in[6];
  const float* siu_bl = (const float*)d_in[7];
  const float* siu_Wr = (const float*)d_in[8];
  const float* lnu_g  = (const float*)d_in[9];
  const float* lnu_b  = (const float*)d_in[10];
  const float* lni_g  = (const float*)d_in[11];
  const float* lni_b  = (const float*)d_in[12];
  const float* phi_eps = (const float*)d_in[13];
  const float* phi_W1  = (const float*)d_in[14];
  const float* phi_b1  = (const float*)d_in[15];
  const float* phi_W2  = (const float*)d_in[16];
  const float* phi_b2  = (const float*)d_in[17];
  const float* pe_W    = (const float*)d_in[18];
  const float* pe_b    = (const float*)d_in[19];
  const int* edge_ui   = (const int*)d_in[20];
  const int* edge_iu   = (const int*)d_in[21];
  const int* edge_hom  = (const int*)d_in[22];

  float* xh  = (float*)d_out;                      // [NH][C] — final output layout
  float* y   = (float*)d_ws;                       // [NH][C]
  float* buf = y + (size_t)NHN * CC;               // [NH][C]  (pe_l, then msum)
  float* agg = buf + (size_t)NHN * CC;             // [NH][PD]
  int*   cnt = (int*)(agg + (size_t)NHN * PDM);    // [NH]

  hipMemsetAsync(agg, 0, (size_t)NHN * PDM * sizeof(float), stream);
  hipMemsetAsync(cnt, 0, (size_t)NHN * sizeof(int), stream);

  k_init<<<(NHN * CC + 255) / 256, 256, 0, stream>>>(x_user, x_item, xh);
  k_count<<<(2 * EHET + 255) / 256, 256, 0, stream>>>(edge_ui + EHET, edge_iu + EHET, cnt);
  k_agg<<<(EHOM * PDM + 255) / 256, 256, 0, stream>>>(edge_hom, edge_hom + EHOM, PE, agg);

  for (int l = 0; l < 2; ++l) {
    k_gin<<<NHN / 4, 128, 0, stream>>>(PE, agg,
        phi_W1 + (size_t)l * PDM * PHM, phi_b1 + (size_t)l * PHM,
        phi_W2 + (size_t)l * PHM * PDM, phi_b2 + (size_t)l * PDM,
        phi_eps + l, buf);
    k_peproj<<<NHN / 16, 128, 0, stream>>>(xh, buf,
        pe_W + (size_t)l * (CC + PDM) * CC, pe_b + (size_t)l * CC, y);
    hipMemsetAsync(buf, 0, (size_t)NHN * CC * sizeof(float), stream);
    // users -> items (dst rows offset by NU), then items -> users
    k_scatter<<<(EHET * CC + 255) / 256, 256, 0, stream>>>(edge_ui, edge_ui + EHET, y, buf, 0, NUQ);
    k_scatter<<<(EHET * CC + 255) / 256, 256, 0, stream>>>(edge_iu, edge_iu + EHET, y, buf, NUQ, 0);
    k_sage_ln<<<NHN / 16, 128, 0, stream>>>(y, buf, cnt,
        siu_Wl + (size_t)l * CC * CC, siu_bl + (size_t)l * CC, siu_Wr + (size_t)l * CC * CC,
        sui_Wl + (size_t)l * CC * CC, sui_bl + (size_t)l * CC, sui_Wr + (size_t)l * CC * CC,
        lnu_g + (size_t)l * CC, lnu_b + (size_t)l * CC,
        lni_g + (size_t)l * CC, lni_b + (size_t)l * CC, xh);
  }
}

// Round 3
// 1411.528 us; speedup vs baseline: 1.8211x; 1.8211x over previous
//
#include <hip/hip_runtime.h>

#define NUQ 100000
#define NIQ 100000
#define NHN 200000
#define CC 128
#define PDM 64
#define PHM 128
#define EHET 500000
#define EHOM 1000000
#define SCAN_CHUNK 2048

typedef __attribute__((ext_vector_type(8))) short bf16x8;
typedef __attribute__((ext_vector_type(4))) float f32x4;

__device__ inline unsigned short f2bf(float x) {
  union { float f; unsigned u; } c; c.f = x;
  unsigned r = c.u + 0x7FFF + ((c.u >> 16) & 1);
  return (unsigned short)(r >> 16);
}

// ---------- init: xh = [x_user; x_item] ----------
__global__ void k_init(const float* __restrict__ xu, const float* __restrict__ xi,
                       float* __restrict__ xh) {
  int i = blockIdx.x * 256 + threadIdx.x;
  const int total = NHN * CC;
  if (i < total) {
    const int uc = NUQ * CC;
    xh[i] = (i < uc) ? xu[i] : xi[i - uc];
  }
}

// ---------- het in-degree counts (combined hom-id space) ----------
__global__ void k_count(const int* __restrict__ eui_dst, const int* __restrict__ eiu_dst,
                        int* __restrict__ cnt) {
  int i = blockIdx.x * 256 + threadIdx.x;
  if (i < EHET) {
    atomicAdd(&cnt[NUQ + eui_dst[i]], 1);          // items
  } else if (i < 2 * EHET) {
    atomicAdd(&cnt[eiu_dst[i - EHET]], 1);         // users
  }
}

__global__ void k_hist(const int* __restrict__ dst, int E, int* __restrict__ cnt) {
  int e = blockIdx.x * 256 + threadIdx.x;
  if (e < E) atomicAdd(&cnt[dst[e]], 1);
}

// ---------- 3-kernel exclusive scan ----------
__global__ __launch_bounds__(256) void k_scan1(const int* __restrict__ in, int n,
                                               int* __restrict__ out, int* __restrict__ blksum) {
  __shared__ int sh[256];
  int b = blockIdx.x, t = threadIdx.x;
  int base = b * SCAN_CHUNK + t * 8;
  int v[8]; int s = 0;
#pragma unroll
  for (int i = 0; i < 8; ++i) {
    int x = (base + i < n) ? in[base + i] : 0;
    v[i] = s;
    s += x;
  }
  sh[t] = s; __syncthreads();
  for (int d = 1; d < 256; d <<= 1) {
    int x = (t >= d) ? sh[t - d] : 0;
    __syncthreads();
    sh[t] += x;
    __syncthreads();
  }
  int texcl = sh[t] - s;
#pragma unroll
  for (int i = 0; i < 8; ++i)
    if (base + i < n) out[base + i] = texcl + v[i];
  if (t == 255) blksum[b] = sh[255];
}

__global__ void k_scan2(const int* __restrict__ blksum, int nb, int* __restrict__ blkoff) {
  __shared__ int sh[256];
  int t = threadIdx.x;
  int x0 = (t < nb) ? blksum[t] : 0;
  sh[t] = x0; __syncthreads();
  for (int d = 1; d < 256; d <<= 1) {
    int x = (t >= d) ? sh[t - d] : 0;
    __syncthreads();
    sh[t] += x;
    __syncthreads();
  }
  if (t < nb) blkoff[t] = sh[t] - x0;
  if (t == 0) blkoff[nb] = sh[255];
}

__global__ void k_scan3(int* __restrict__ off, int n, const int* __restrict__ blkoff, int nb) {
  int i = blockIdx.x * 256 + threadIdx.x;
  if (i < n) off[i] += blkoff[i >> 11];
  else if (i == n) off[n] = blkoff[nb];
}

// ---------- CSR fill via atomic cursor ----------
__global__ void k_fill(const int* __restrict__ src, const int* __restrict__ dst, int E,
                       const int* __restrict__ off, int* __restrict__ cur, int* __restrict__ out) {
  int e = blockIdx.x * 256 + threadIdx.x;
  if (e < E) {
    int d = dst[e];
    int p = atomicAdd(&cur[d], 1);
    out[off[d] + p] = src[e];
  }
}

// ---------- GIN neighborhood sum via CSR gather (one wave per node) ----------
__global__ __launch_bounds__(256) void k_aggcsr(const int* __restrict__ off, const int* __restrict__ idx,
                                                const float* __restrict__ pe, float* __restrict__ agg) {
  int wave = threadIdx.x >> 6, lane = threadIdx.x & 63;
  int n = blockIdx.x * 4 + wave;
  if (n >= NHN) return;
  int e0 = off[n], e1 = off[n + 1];
  float s = 0.f;
  for (int e = e0; e < e1; ++e)
    s += pe[(size_t)idx[e] * PDM + lane];
  agg[(size_t)n * PDM + lane] = s;
}

// ---------- fused GIN MLP: pe_l = relu(h@W1+b1)@W2+b2, h=(1+eps)*PE+agg ----------
__global__ __launch_bounds__(128) void k_gin(
    const float* __restrict__ pe, const float* __restrict__ agg,
    const float* __restrict__ W1, const float* __restrict__ b1,
    const float* __restrict__ W2, const float* __restrict__ b2,
    const float* __restrict__ eps_p, float* __restrict__ out) {
  __shared__ float h[4][PDM];
  __shared__ float hid[4][PHM];
  int row0 = blockIdx.x * 4;
  int t = threadIdx.x;
  float e1 = 1.0f + eps_p[0];
  if (t < PDM) {
#pragma unroll
    for (int r = 0; r < 4; ++r)
      h[r][t] = e1 * pe[(row0 + r) * PDM + t] + agg[(row0 + r) * PDM + t];
  }
  __syncthreads();
  float a0 = b1[t], a1 = a0, a2 = a0, a3 = a0;
  for (int k = 0; k < PDM; ++k) {
    float w = W1[k * PHM + t];
    a0 += h[0][k] * w; a1 += h[1][k] * w; a2 += h[2][k] * w; a3 += h[3][k] * w;
  }
  hid[0][t] = fmaxf(a0, 0.f); hid[1][t] = fmaxf(a1, 0.f);
  hid[2][t] = fmaxf(a2, 0.f); hid[3][t] = fmaxf(a3, 0.f);
  __syncthreads();
  int d = t & 63, rb = t >> 6;
  float o0 = b2[d], o1 = b2[d];
  for (int k = 0; k < PHM; ++k) {
    float w = W2[k * PDM + d];
    o0 += hid[rb][k] * w;
    o1 += hid[rb + 2][k] * w;
  }
  out[(row0 + rb) * PDM + d] = o0;
  out[(row0 + rb + 2) * PDM + d] = o1;
}

// ---------- pack f32 weights (Ksub x 128) into MFMA B-fragment order (bf16) ----------
// lane l holds B[k = kk*32 + 8*(l>>4) + j][col = ct*16 + (l&15)], j=0..7 contiguous 16B
__global__ void k_pack(const float* __restrict__ W, int Ksub, int kkBase, int KKtot,
                       unsigned short* __restrict__ out) {
  int i = blockIdx.x * 256 + threadIdx.x;
  if (i < Ksub * 128) {
    int k = i >> 7, n = i & 127;
    int kk = kkBase + (k >> 5);
    int lane = (n & 15) + (((k >> 3) & 3) << 4);
    int j = k & 7;
    int o16 = ((n >> 4) * KKtot + kk) * 64 + lane;
    out[o16 * 8 + j] = f2bf(W[i]);
  }
}

// ---------- peproj: y = concat(xh, pe_l) @ pe_W + pe_b  (K=192, bf16 MFMA) ----------
__global__ __launch_bounds__(256) void k_peproj_mfma(
    const float* __restrict__ xh, const float* __restrict__ pe_l,
    const unsigned short* __restrict__ Bp, const float* __restrict__ bias,
    float* __restrict__ y) {
  __shared__ __align__(16) char Abuf[32 * 384];
  int t = threadIdx.x, wave = t >> 6, lane = t & 63;
  int row0 = blockIdx.x * 32;
  // stage xh (cols 0..127 -> chunks 0..15), bf16, XOR-swizzled
  for (int i = t; i < 32 * 64; i += 256) {
    int r = i >> 6, cp = i & 63;
    float2 v = *reinterpret_cast<const float2*>(&xh[(size_t)(row0 + r) * CC + cp * 2]);
    unsigned pv = (unsigned)f2bf(v.x) | ((unsigned)f2bf(v.y) << 16);
    int chunk = (cp >> 2) ^ (r & 7);
    *reinterpret_cast<unsigned*>(Abuf + r * 384 + chunk * 16 + (cp & 3) * 4) = pv;
  }
  // stage pe_l (cols 0..63 -> chunks 16..23)
  for (int i = t; i < 32 * 32; i += 256) {
    int r = i >> 5, cp = i & 31;
    float2 v = *reinterpret_cast<const float2*>(&pe_l[(size_t)(row0 + r) * PDM + cp * 2]);
    unsigned pv = (unsigned)f2bf(v.x) | ((unsigned)f2bf(v.y) << 16);
    int chunk = (16 + (cp >> 2)) ^ (r & 7);
    *reinterpret_cast<unsigned*>(Abuf + r * 384 + chunk * 16 + (cp & 3) * 4) = pv;
  }
  __syncthreads();
  int rt = wave & 1, ctb = (wave >> 1) * 4;
  f32x4 acc0 = {0.f, 0.f, 0.f, 0.f}, acc1 = acc0, acc2 = acc0, acc3 = acc0;
  int arow = rt * 16 + (lane & 15);
  const char* abase = Abuf + arow * 384;
  int axor = arow & 7;
  const bf16x8* bp0 = reinterpret_cast<const bf16x8*>(Bp);
  for (int kk = 0; kk < 6; ++kk) {
    bf16x8 a = *reinterpret_cast<const bf16x8*>(abase + (((kk * 4 + (lane >> 4)) ^ axor) * 16));
    const bf16x8* bp = bp0 + (size_t)kk * 64 + lane;
    acc0 = __builtin_amdgcn_mfma_f32_16x16x32_bf16(a, bp[(size_t)(ctb + 0) * 6 * 64], acc0, 0, 0, 0);
    acc1 = __builtin_amdgcn_mfma_f32_16x16x32_bf16(a, bp[(size_t)(ctb + 1) * 6 * 64], acc1, 0, 0, 0);
    acc2 = __builtin_amdgcn_mfma_f32_16x16x32_bf16(a, bp[(size_t)(ctb + 2) * 6 * 64], acc2, 0, 0, 0);
    acc3 = __builtin_amdgcn_mfma_f32_16x16x32_bf16(a, bp[(size_t)(ctb + 3) * 6 * 64], acc3, 0, 0, 0);
  }
  int prow0 = row0 + rt * 16 + ((lane >> 4) << 2);
  int c0 = ctb * 16 + (lane & 15);
  float b0 = bias[c0], b1 = bias[c0 + 16], b2 = bias[c0 + 32], b3 = bias[c0 + 48];
#pragma unroll
  for (int q = 0; q < 4; ++q) {
    size_t rb = (size_t)(prow0 + q) * CC;
    y[rb + c0]      = acc0[q] + b0;
    y[rb + c0 + 16] = acc1[q] + b1;
    y[rb + c0 + 32] = acc2[q] + b2;
    y[rb + c0 + 48] = acc3[q] + b3;
  }
}

// ---------- fused: CSR mean-gather + dual GEMM (K=256 concat) + bias + LN + ReLU ----------
__global__ __launch_bounds__(256) void k_sage_mfma(
    const float* __restrict__ y,
    const int* __restrict__ offU, const int* __restrict__ idxU,
    const int* __restrict__ offI, const int* __restrict__ idxI,
    const int* __restrict__ cnt,
    const unsigned short* __restrict__ BpU, const unsigned short* __restrict__ BpI,
    const float* __restrict__ blU, const float* __restrict__ blI,
    const float* __restrict__ gU, const float* __restrict__ beU,
    const float* __restrict__ gI, const float* __restrict__ beI,
    float* __restrict__ xh) {
  __shared__ __align__(16) char Abuf[32 * 512];
  __shared__ float preLN[32][132];
  __shared__ float stat[32][2];
  int t = threadIdx.x, wave = t >> 6, lane = t & 63;
  int row0 = blockIdx.x * 32;
  bool isU = row0 < NUQ;
  const int* off = isU ? offU : offI;
  const int* idx = isU ? idxU : idxI;
  int dBase = isU ? 0 : NUQ;
  int sBase = isU ? NUQ : 0;   // users gather from item rows and vice versa
  const unsigned short* Bp = isU ? BpU : BpI;
  const float* bl = isU ? blU : blI;
  const float* g  = isU ? gU : gI;
  const float* be = isU ? beU : beI;

  // stage: wave w owns rows w*8 .. w*8+7 (mean -> chunks 0..15, own y -> 16..31)
  for (int r8 = 0; r8 < 8; ++r8) {
    int r = wave * 8 + r8;
    int d = row0 + r;
    int e0 = off[d - dBase], e1 = off[d - dBase + 1];
    float sx = 0.f, sy = 0.f;
    for (int e = e0; e < e1; ++e) {
      int srow = sBase + idx[e];
      float2 v = *reinterpret_cast<const float2*>(&y[(size_t)srow * CC + lane * 2]);
      sx += v.x; sy += v.y;
    }
    float inv = 1.0f / fmaxf((float)cnt[d], 1.0f);
    unsigned pm = (unsigned)f2bf(sx * inv) | ((unsigned)f2bf(sy * inv) << 16);
    int chunk = (lane >> 2) ^ (r & 7);
    *reinterpret_cast<unsigned*>(Abuf + r * 512 + chunk * 16 + (lane & 3) * 4) = pm;
    float2 v2 = *reinterpret_cast<const float2*>(&y[(size_t)(row0 + r) * CC + lane * 2]);
    unsigned pv = (unsigned)f2bf(v2.x) | ((unsigned)f2bf(v2.y) << 16);
    int chunk2 = (16 + (lane >> 2)) ^ (r & 7);
    *reinterpret_cast<unsigned*>(Abuf + r * 512 + chunk2 * 16 + (lane & 3) * 4) = pv;
  }
  __syncthreads();
  // MFMA: K=256 over [mean | y], B = [Wl; Wr] prepacked
  int rt = wave & 1, ctb = (wave >> 1) * 4;
  f32x4 acc0 = {0.f, 0.f, 0.f, 0.f}, acc1 = acc0, acc2 = acc0, acc3 = acc0;
  int arow = rt * 16 + (lane & 15);
  const char* abase = Abuf + arow * 512;
  int axor = arow & 7;
  const bf16x8* bp0 = reinterpret_cast<const bf16x8*>(Bp);
  for (int kk = 0; kk < 8; ++kk) {
    bf16x8 a = *reinterpret_cast<const bf16x8*>(abase + (((kk * 4 + (lane >> 4)) ^ axor) * 16));
    const bf16x8* bp = bp0 + (size_t)kk * 64 + lane;
    acc0 = __builtin_amdgcn_mfma_f32_16x16x32_bf16(a, bp[(size_t)(ctb + 0) * 8 * 64], acc0, 0, 0, 0);
    acc1 = __builtin_amdgcn_mfma_f32_16x16x32_bf16(a, bp[(size_t)(ctb + 1) * 8 * 64], acc1, 0, 0, 0);
    acc2 = __builtin_amdgcn_mfma_f32_16x16x32_bf16(a, bp[(size_t)(ctb + 2) * 8 * 64], acc2, 0, 0, 0);
    acc3 = __builtin_amdgcn_mfma_f32_16x16x32_bf16(a, bp[(size_t)(ctb + 3) * 8 * 64], acc3, 0, 0, 0);
  }
  // epilogue: bias -> preLN (padded stride 132 -> conflict-free)
  {
    int prow = rt * 16 + ((lane >> 4) << 2);
    int c0 = ctb * 16 + (lane & 15);
    float b0 = bl[c0], b1 = bl[c0 + 16], b2 = bl[c0 + 32], b3 = bl[c0 + 48];
#pragma unroll
    for (int q = 0; q < 4; ++q) {
      preLN[prow + q][c0]      = acc0[q] + b0;
      preLN[prow + q][c0 + 16] = acc1[q] + b1;
      preLN[prow + q][c0 + 32] = acc2[q] + b2;
      preLN[prow + q][c0 + 48] = acc3[q] + b3;
    }
  }
  __syncthreads();
  // LN stats: 8 threads per row
  {
    int rr = t >> 3, j = t & 7;
    float s = 0.f, sq = 0.f;
#pragma unroll
    for (int i = 0; i < 16; ++i) { float v = preLN[rr][j + 8 * i]; s += v; sq += v * v; }
    s += __shfl_xor(s, 1); sq += __shfl_xor(sq, 1);
    s += __shfl_xor(s, 2); sq += __shfl_xor(sq, 2);
    s += __shfl_xor(s, 4); sq += __shfl_xor(sq, 4);
    if (j == 0) {
      float mu = s * (1.0f / CC);
      float var = sq * (1.0f / CC) - mu * mu;
      stat[rr][0] = mu;
      stat[rr][1] = rsqrtf(var + 1e-5f);
    }
  }
  __syncthreads();
  for (int i = t; i < 32 * CC; i += 256) {
    int r = i >> 7, c = i & 127;
    float v = (preLN[r][c] - stat[r][0]) * stat[r][1] * g[c] + be[c];
    xh[(size_t)(row0 + r) * CC + c] = fmaxf(v, 0.f);
  }
}

extern "C" void kernel_launch(void* const* d_in, const int* in_sizes, int n_in,
                              void* d_out, int out_size, void* d_ws, size_t ws_size,
                              hipStream_t stream) {
  const float* x_user = (const float*)d_in[0];
  const float* x_item = (const float*)d_in[1];
  const float* PE     = (const float*)d_in[2];
  const float* sui_Wl = (const float*)d_in[3];
  const float* sui_bl = (const float*)d_in[4];
  const float* sui_Wr = (const float*)d_in[5];
  const float* siu_Wl = (const float*)d_in[6];
  const float* siu_bl = (const float*)d_in[7];
  const float* siu_Wr = (const float*)d_in[8];
  const float* lnu_g  = (const float*)d_in[9];
  const float* lnu_b  = (const float*)d_in[10];
  const float* lni_g  = (const float*)d_in[11];
  const float* lni_b  = (const float*)d_in[12];
  const float* phi_eps = (const float*)d_in[13];
  const float* phi_W1  = (const float*)d_in[14];
  const float* phi_b1  = (const float*)d_in[15];
  const float* phi_W2  = (const float*)d_in[16];
  const float* phi_b2  = (const float*)d_in[17];
  const float* pe_W    = (const float*)d_in[18];
  const float* pe_b    = (const float*)d_in[19];
  const int* edge_ui   = (const int*)d_in[20];
  const int* edge_iu   = (const int*)d_in[21];
  const int* edge_hom  = (const int*)d_in[22];

  float* xh  = (float*)d_out;                       // [NH][C]
  float* y    = (float*)d_ws;                       // [NH][C]
  float* pe_l = y + (size_t)NHN * CC;               // [NH][PD]
  float* agg  = pe_l + (size_t)NHN * PDM;           // [NH][PD]
  int* ip = (int*)(agg + (size_t)NHN * PDM);
  int* cnt      = ip;             ip += NHN;        // het in-degree (hom ids)
  int* cnt_hom  = ip;             ip += NHN;
  int* off_iu   = ip;             ip += NUQ + 1;    // users' in-edges (from items)
  int* off_ui   = ip;             ip += NIQ + 1;    // items' in-edges (from users)
  int* off_hom  = ip;             ip += NHN + 1;
  int* idx_ui   = ip;             ip += EHET;
  int* idx_iu   = ip;             ip += EHET;
  int* idx_hom  = ip;             ip += EHOM;
  int* cur_u    = ip;             ip += NUQ;
  int* cur_i    = ip;             ip += NIQ;
  int* cur_h    = ip;             ip += NHN;
  int* blksum   = ip;             ip += 256;
  int* blkoff   = ip;             ip += 257;
  // 16B-align the bf16 pack region
  unsigned short* packs = (unsigned short*)((((size_t)(ip)) + 15) & ~(size_t)15);
  unsigned short* sageP = packs;                    // [L][2 types] x 32768
  unsigned short* peP   = packs + 4 * 32768;        // [L] x 24576

  hipMemsetAsync(cnt, 0, NHN * sizeof(int), stream);
  hipMemsetAsync(cnt_hom, 0, NHN * sizeof(int), stream);
  hipMemsetAsync(cur_u, 0, NUQ * sizeof(int), stream);
  hipMemsetAsync(cur_i, 0, NIQ * sizeof(int), stream);
  hipMemsetAsync(cur_h, 0, NHN * sizeof(int), stream);

  k_init<<<(NHN * CC + 255) / 256, 256, 0, stream>>>(x_user, x_item, xh);
  k_count<<<(2 * EHET + 255) / 256, 256, 0, stream>>>(edge_ui + EHET, edge_iu + EHET, cnt);
  k_hist<<<(EHOM + 255) / 256, 256, 0, stream>>>(edge_hom + EHOM, EHOM, cnt_hom);

  // scans: iu (users, n=NUQ), ui (items, n=NIQ, input cnt+NUQ), hom (n=NHN)
  {
    int n = NUQ, nb = (n + SCAN_CHUNK - 1) / SCAN_CHUNK;
    k_scan1<<<nb, 256, 0, stream>>>(cnt, n, off_iu, blksum);
    k_scan2<<<1, 256, 0, stream>>>(blksum, nb, blkoff);
    k_scan3<<<(n + 256) / 256 + 1, 256, 0, stream>>>(off_iu, n, blkoff, nb);
  }
  {
    int n = NIQ, nb = (n + SCAN_CHUNK - 1) / SCAN_CHUNK;
    k_scan1<<<nb, 256, 0, stream>>>(cnt + NUQ, n, off_ui, blksum);
    k_scan2<<<1, 256, 0, stream>>>(blksum, nb, blkoff);
    k_scan3<<<(n + 256) / 256 + 1, 256, 0, stream>>>(off_ui, n, blkoff, nb);
  }
  {
    int n = NHN, nb = (n + SCAN_CHUNK - 1) / SCAN_CHUNK;
    k_scan1<<<nb, 256, 0, stream>>>(cnt_hom, n, off_hom, blksum);
    k_scan2<<<1, 256, 0, stream>>>(blksum, nb, blkoff);
    k_scan3<<<(n + 256) / 256 + 1, 256, 0, stream>>>(off_hom, n, blkoff, nb);
  }
  k_fill<<<(EHET + 255) / 256, 256, 0, stream>>>(edge_ui, edge_ui + EHET, EHET, off_ui, cur_i, idx_ui);
  k_fill<<<(EHET + 255) / 256, 256, 0, stream>>>(edge_iu, edge_iu + EHET, EHET, off_iu, cur_u, idx_iu);
  k_fill<<<(EHOM + 255) / 256, 256, 0, stream>>>(edge_hom, edge_hom + EHOM, EHOM, off_hom, cur_h, idx_hom);

  k_aggcsr<<<NHN / 4, 256, 0, stream>>>(off_hom, idx_hom, PE, agg);

  // weight prepack (bf16 fragment order)
  for (int l = 0; l < 2; ++l) {
    k_pack<<<64, 256, 0, stream>>>(siu_Wl + (size_t)l * CC * CC, CC, 0, 8, sageP + (size_t)(l * 2) * 32768);
    k_pack<<<64, 256, 0, stream>>>(siu_Wr + (size_t)l * CC * CC, CC, 4, 8, sageP + (size_t)(l * 2) * 32768);
    k_pack<<<64, 256, 0, stream>>>(sui_Wl + (size_t)l * CC * CC, CC, 0, 8, sageP + (size_t)(l * 2 + 1) * 32768);
    k_pack<<<64, 256, 0, stream>>>(sui_Wr + (size_t)l * CC * CC, CC, 4, 8, sageP + (size_t)(l * 2 + 1) * 32768);
    k_pack<<<96, 256, 0, stream>>>(pe_W + (size_t)l * (CC + PDM) * CC, CC + PDM, 0, 6, peP + (size_t)l * 24576);
  }

  for (int l = 0; l < 2; ++l) {
    k_gin<<<NHN / 4, 128, 0, stream>>>(PE, agg,
        phi_W1 + (size_t)l * PDM * PHM, phi_b1 + (size_t)l * PHM,
        phi_W2 + (size_t)l * PHM * PDM, phi_b2 + (size_t)l * PDM,
        phi_eps + l, pe_l);
    k_peproj_mfma<<<NHN / 32, 256, 0, stream>>>(xh, pe_l,
        peP + (size_t)l * 24576, pe_b + (size_t)l * CC, y);
    k_sage_mfma<<<NHN / 32, 256, 0, stream>>>(y,
        off_iu, idx_iu, off_ui, idx_ui, cnt,
        sageP + (size_t)(l * 2) * 32768, sageP + (size_t)(l * 2 + 1) * 32768,
        siu_bl + (size_t)l * CC, sui_bl + (size_t)l * CC,
        lnu_g + (size_t)l * CC, lnu_b + (size_t)l * CC,
        lni_g + (size_t)l * CC, lni_b + (size_t)l * CC, xh);
  }
}

// Round 4
// 855.134 us; speedup vs baseline: 3.0060x; 1.6507x over previous
//
#include <hip/hip_runtime.h>

#define NUQ 100000
#define NIQ 100000
#define NHN 200000
#define CC 128
#define PDM 64
#define PHM 128
#define EHET 500000
#define EHOM 1000000
#define SCAN_CHUNK 2048

typedef __attribute__((ext_vector_type(8))) short bf16x8;
typedef __attribute__((ext_vector_type(4))) float f32x4;

__device__ inline unsigned short f2bf(float x) {
  union { float f; unsigned u; } c; c.f = x;
  unsigned r = c.u + 0x7FFF + ((c.u >> 16) & 1);
  return (unsigned short)(r >> 16);
}
__device__ inline float bflo(unsigned u) { union { unsigned u; float f; } c; c.u = u << 16; return c.f; }
__device__ inline float bfhi(unsigned u) { union { unsigned u; float f; } c; c.u = u & 0xffff0000u; return c.f; }

// ---------- het in-degree counts (combined hom-id space) ----------
__global__ void k_count(const int* __restrict__ eui_dst, const int* __restrict__ eiu_dst,
                        int* __restrict__ cnt) {
  int i = blockIdx.x * 256 + threadIdx.x;
  if (i < EHET) {
    atomicAdd(&cnt[NUQ + eui_dst[i]], 1);          // items
  } else if (i < 2 * EHET) {
    atomicAdd(&cnt[eiu_dst[i - EHET]], 1);         // users
  }
}

__global__ void k_hist(const int* __restrict__ dst, int E, int* __restrict__ cnt) {
  int e = blockIdx.x * 256 + threadIdx.x;
  if (e < E) atomicAdd(&cnt[dst[e]], 1);
}

// ---------- 3-kernel exclusive scan ----------
__global__ __launch_bounds__(256) void k_scan1(const int* __restrict__ in, int n,
                                               int* __restrict__ out, int* __restrict__ blksum) {
  __shared__ int sh[256];
  int b = blockIdx.x, t = threadIdx.x;
  int base = b * SCAN_CHUNK + t * 8;
  int v[8]; int s = 0;
#pragma unroll
  for (int i = 0; i < 8; ++i) {
    int x = (base + i < n) ? in[base + i] : 0;
    v[i] = s;
    s += x;
  }
  sh[t] = s; __syncthreads();
  for (int d = 1; d < 256; d <<= 1) {
    int x = (t >= d) ? sh[t - d] : 0;
    __syncthreads();
    sh[t] += x;
    __syncthreads();
  }
  int texcl = sh[t] - s;
#pragma unroll
  for (int i = 0; i < 8; ++i)
    if (base + i < n) out[base + i] = texcl + v[i];
  if (t == 255) blksum[b] = sh[255];
}

__global__ void k_scan2(const int* __restrict__ blksum, int nb, int* __restrict__ blkoff) {
  __shared__ int sh[256];
  int t = threadIdx.x;
  int x0 = (t < nb) ? blksum[t] : 0;
  sh[t] = x0; __syncthreads();
  for (int d = 1; d < 256; d <<= 1) {
    int x = (t >= d) ? sh[t - d] : 0;
    __syncthreads();
    sh[t] += x;
    __syncthreads();
  }
  if (t < nb) blkoff[t] = sh[t] - x0;
  if (t == 0) blkoff[nb] = sh[255];
}

__global__ void k_scan3(int* __restrict__ off, int n, const int* __restrict__ blkoff, int nb) {
  int i = blockIdx.x * 256 + threadIdx.x;
  if (i < n) off[i] += blkoff[i >> 11];
  else if (i == n) off[n] = blkoff[nb];
}

// ---------- CSR fill via atomic cursor ----------
__global__ void k_fill(const int* __restrict__ src, const int* __restrict__ dst, int E,
                       const int* __restrict__ off, int* __restrict__ cur, int* __restrict__ out) {
  int e = blockIdx.x * 256 + threadIdx.x;
  if (e < E) {
    int d = dst[e];
    int p = atomicAdd(&cur[d], 1);
    out[off[d] + p] = src[e];
  }
}

// ---------- PE -> bf16 copy ----------
__global__ __launch_bounds__(256) void k_pe2bf(const float* __restrict__ pe,
                                               unsigned* __restrict__ out) {
  int i = blockIdx.x * 256 + threadIdx.x;
  if (i < NHN * PDM / 2) {
    float2 v = *reinterpret_cast<const float2*>(&pe[(size_t)i * 2]);
    out[i] = (unsigned)f2bf(v.x) | ((unsigned)f2bf(v.y) << 16);
  }
}

// ---------- GIN neighborhood sum via CSR gather (half-wave per node, bf16 src) ----------
__global__ __launch_bounds__(256) void k_aggcsr(const int* __restrict__ off, const int* __restrict__ idx,
                                                const unsigned short* __restrict__ pe_bf,
                                                float* __restrict__ agg) {
  int half = threadIdx.x >> 5, hl = threadIdx.x & 31;
  int n = blockIdx.x * 8 + half;
  int e0 = off[n], e1 = off[n + 1];
  float sx = 0.f, sy = 0.f, tx = 0.f, ty = 0.f;
  int e = e0;
  for (; e + 2 <= e1; e += 2) {
    unsigned u0 = *reinterpret_cast<const unsigned*>(&pe_bf[(size_t)idx[e] * PDM + hl * 2]);
    unsigned u1 = *reinterpret_cast<const unsigned*>(&pe_bf[(size_t)idx[e + 1] * PDM + hl * 2]);
    sx += bflo(u0); sy += bfhi(u0); tx += bflo(u1); ty += bfhi(u1);
  }
  if (e < e1) {
    unsigned u0 = *reinterpret_cast<const unsigned*>(&pe_bf[(size_t)idx[e] * PDM + hl * 2]);
    sx += bflo(u0); sy += bfhi(u0);
  }
  float2 o = { sx + tx, sy + ty };
  *reinterpret_cast<float2*>(&agg[(size_t)n * PDM + hl * 2]) = o;
}

// ---------- pack f32 weights (Ksub x NC) into MFMA B-fragment order (bf16) ----------
// lane l holds B[k = kk*32 + 8*(l>>4) + j][col = ct*16 + (l&15)], j=0..7 contiguous 16B
__global__ void k_pack(const float* __restrict__ W, int Ksub, int NC, int kkBase, int KKtot,
                       unsigned short* __restrict__ out) {
  int i = blockIdx.x * 256 + threadIdx.x;
  if (i < Ksub * NC) {
    int k = i / NC, n = i % NC;
    int kk = kkBase + (k >> 5);
    int lane = (n & 15) + (((k >> 3) & 3) << 4);
    int j = k & 7;
    int o16 = ((n >> 4) * KKtot + kk) * 64 + lane;
    out[o16 * 8 + j] = f2bf(W[i]);
  }
}

// ---------- fused GIN MLP via MFMA: pe_l = relu(h@W1+b1)@W2+b2 (bf16 out) ----------
__global__ __launch_bounds__(256) void k_gin_mfma(
    const float* __restrict__ pe, const float* __restrict__ agg,
    const unsigned short* __restrict__ B1p, const float* __restrict__ b1,
    const unsigned short* __restrict__ B2p, const float* __restrict__ b2,
    const float* __restrict__ eps_p, unsigned short* __restrict__ pel) {
  __shared__ __align__(16) char Ah[32 * 128];
  __shared__ __align__(16) char Hh[32 * 256];
  int t = threadIdx.x, wave = t >> 6, lane = t & 63;
  int row0 = blockIdx.x * 32;
  float e1 = 1.0f + eps_p[0];
  for (int i = t; i < 32 * 32; i += 256) {
    int r = i >> 5, cp = i & 31;
    float2 p2 = *reinterpret_cast<const float2*>(&pe[(size_t)(row0 + r) * PDM + cp * 2]);
    float2 a2 = *reinterpret_cast<const float2*>(&agg[(size_t)(row0 + r) * PDM + cp * 2]);
    unsigned pv = (unsigned)f2bf(e1 * p2.x + a2.x) | ((unsigned)f2bf(e1 * p2.y + a2.y) << 16);
    int chunk = (cp >> 2) ^ (r & 7);
    *reinterpret_cast<unsigned*>(Ah + r * 128 + chunk * 16 + (cp & 3) * 4) = pv;
  }
  __syncthreads();
  int rt = wave & 1, ctb = (wave >> 1) * 4;
  int arow = rt * 16 + (lane & 15);
  int axor = arow & 7;
  // GEMM1: [32x64] @ [64x128]
  {
    f32x4 acc0 = {0.f, 0.f, 0.f, 0.f}, acc1 = acc0, acc2 = acc0, acc3 = acc0;
    const char* abase = Ah + arow * 128;
    const bf16x8* bv = reinterpret_cast<const bf16x8*>(B1p);
    for (int kk = 0; kk < 2; ++kk) {
      bf16x8 a = *reinterpret_cast<const bf16x8*>(abase + (((kk * 4 + (lane >> 4)) ^ axor) * 16));
      const bf16x8* bp = bv + (size_t)kk * 64 + lane;
      acc0 = __builtin_amdgcn_mfma_f32_16x16x32_bf16(a, bp[(size_t)(ctb + 0) * 2 * 64], acc0, 0, 0, 0);
      acc1 = __builtin_amdgcn_mfma_f32_16x16x32_bf16(a, bp[(size_t)(ctb + 1) * 2 * 64], acc1, 0, 0, 0);
      acc2 = __builtin_amdgcn_mfma_f32_16x16x32_bf16(a, bp[(size_t)(ctb + 2) * 2 * 64], acc2, 0, 0, 0);
      acc3 = __builtin_amdgcn_mfma_f32_16x16x32_bf16(a, bp[(size_t)(ctb + 3) * 2 * 64], acc3, 0, 0, 0);
    }
    int prow = rt * 16 + ((lane >> 4) << 2);
    int c0 = ctb * 16 + (lane & 15);
    float bb0 = b1[c0], bb1 = b1[c0 + 16], bb2 = b1[c0 + 32], bb3 = b1[c0 + 48];
    int j2 = (c0 & 7) * 2, cb = c0 >> 3;
#pragma unroll
    for (int q = 0; q < 4; ++q) {
      int rw = prow + q, rx = rw & 7;
      char* hb = Hh + rw * 256;
      *reinterpret_cast<unsigned short*>(hb + (((cb + 0) ^ rx) * 16) + j2) = f2bf(fmaxf(acc0[q] + bb0, 0.f));
      *reinterpret_cast<unsigned short*>(hb + (((cb + 2) ^ rx) * 16) + j2) = f2bf(fmaxf(acc1[q] + bb1, 0.f));
      *reinterpret_cast<unsigned short*>(hb + (((cb + 4) ^ rx) * 16) + j2) = f2bf(fmaxf(acc2[q] + bb2, 0.f));
      *reinterpret_cast<unsigned short*>(hb + (((cb + 6) ^ rx) * 16) + j2) = f2bf(fmaxf(acc3[q] + bb3, 0.f));
    }
  }
  __syncthreads();
  // GEMM2: [32x128] @ [128x64]
  {
    int ct2 = (wave >> 1) * 2;
    f32x4 d0 = {0.f, 0.f, 0.f, 0.f}, d1 = d0;
    const char* hbase = Hh + arow * 256;
    const bf16x8* bv = reinterpret_cast<const bf16x8*>(B2p);
    for (int kk = 0; kk < 4; ++kk) {
      bf16x8 a = *reinterpret_cast<const bf16x8*>(hbase + (((kk * 4 + (lane >> 4)) ^ axor) * 16));
      const bf16x8* bp = bv + (size_t)kk * 64 + lane;
      d0 = __builtin_amdgcn_mfma_f32_16x16x32_bf16(a, bp[(size_t)(ct2 + 0) * 4 * 64], d0, 0, 0, 0);
      d1 = __builtin_amdgcn_mfma_f32_16x16x32_bf16(a, bp[(size_t)(ct2 + 1) * 4 * 64], d1, 0, 0, 0);
    }
    int prow0 = row0 + rt * 16 + ((lane >> 4) << 2);
    int c0 = ct2 * 16 + (lane & 15);
    float bb0 = b2[c0], bb1 = b2[c0 + 16];
#pragma unroll
    for (int q = 0; q < 4; ++q) {
      pel[(size_t)(prow0 + q) * PDM + c0] = f2bf(d0[q] + bb0);
      pel[(size_t)(prow0 + q) * PDM + c0 + 16] = f2bf(d1[q] + bb1);
    }
  }
}

// ---------- peproj: y = concat(x, pe_l) @ pe_W + pe_b  (K=192, bf16 MFMA, bf16 out) ----------
__global__ __launch_bounds__(256) void k_peproj_mfma(
    const float* __restrict__ xu, const float* __restrict__ xi,
    const unsigned short* __restrict__ pel,
    const unsigned short* __restrict__ Bp, const float* __restrict__ bias,
    unsigned short* __restrict__ y_bf) {
  __shared__ __align__(16) char Abuf[32 * 384];
  int t = threadIdx.x, wave = t >> 6, lane = t & 63;
  int row0 = blockIdx.x * 32;
  const float* xs = (row0 < NUQ) ? xu : xi;
  int rbase = (row0 < NUQ) ? row0 : row0 - NUQ;
  // stage x (cols 0..127 -> chunks 0..15), f32 -> bf16, XOR-swizzled
  for (int i = t; i < 32 * 64; i += 256) {
    int r = i >> 6, cp = i & 63;
    float2 v = *reinterpret_cast<const float2*>(&xs[(size_t)(rbase + r) * CC + cp * 2]);
    unsigned pv = (unsigned)f2bf(v.x) | ((unsigned)f2bf(v.y) << 16);
    int chunk = (cp >> 2) ^ (r & 7);
    *reinterpret_cast<unsigned*>(Abuf + r * 384 + chunk * 16 + (cp & 3) * 4) = pv;
  }
  // stage pe_l (bf16, raw copy -> chunks 16..23)
  for (int i = t; i < 32 * 32; i += 256) {
    int r = i >> 5, cp = i & 31;
    unsigned pv = *reinterpret_cast<const unsigned*>(&pel[(size_t)(row0 + r) * PDM + cp * 2]);
    int chunk = (16 + (cp >> 2)) ^ (r & 7);
    *reinterpret_cast<unsigned*>(Abuf + r * 384 + chunk * 16 + (cp & 3) * 4) = pv;
  }
  __syncthreads();
  int rt = wave & 1, ctb = (wave >> 1) * 4;
  f32x4 acc0 = {0.f, 0.f, 0.f, 0.f}, acc1 = acc0, acc2 = acc0, acc3 = acc0;
  int arow = rt * 16 + (lane & 15);
  const char* abase = Abuf + arow * 384;
  int axor = arow & 7;
  const bf16x8* bp0 = reinterpret_cast<const bf16x8*>(Bp);
  for (int kk = 0; kk < 6; ++kk) {
    bf16x8 a = *reinterpret_cast<const bf16x8*>(abase + (((kk * 4 + (lane >> 4)) ^ axor) * 16));
    const bf16x8* bp = bp0 + (size_t)kk * 64 + lane;
    acc0 = __builtin_amdgcn_mfma_f32_16x16x32_bf16(a, bp[(size_t)(ctb + 0) * 6 * 64], acc0, 0, 0, 0);
    acc1 = __builtin_amdgcn_mfma_f32_16x16x32_bf16(a, bp[(size_t)(ctb + 1) * 6 * 64], acc1, 0, 0, 0);
    acc2 = __builtin_amdgcn_mfma_f32_16x16x32_bf16(a, bp[(size_t)(ctb + 2) * 6 * 64], acc2, 0, 0, 0);
    acc3 = __builtin_amdgcn_mfma_f32_16x16x32_bf16(a, bp[(size_t)(ctb + 3) * 6 * 64], acc3, 0, 0, 0);
  }
  int prow0 = row0 + rt * 16 + ((lane >> 4) << 2);
  int c0 = ctb * 16 + (lane & 15);
  float b0 = bias[c0], b1 = bias[c0 + 16], b2 = bias[c0 + 32], b3 = bias[c0 + 48];
#pragma unroll
  for (int q = 0; q < 4; ++q) {
    size_t rb = (size_t)(prow0 + q) * CC;
    y_bf[rb + c0]      = f2bf(acc0[q] + b0);
    y_bf[rb + c0 + 16] = f2bf(acc1[q] + b1);
    y_bf[rb + c0 + 32] = f2bf(acc2[q] + b2);
    y_bf[rb + c0 + 48] = f2bf(acc3[q] + b3);
  }
}

// ---------- fused: CSR mean-gather (bf16 y) + dual GEMM (K=256) + bias + LN + ReLU ----------
__global__ __launch_bounds__(256) void k_sage_mfma(
    const unsigned short* __restrict__ y_bf,
    const int* __restrict__ offU, const int* __restrict__ idxU,
    const int* __restrict__ offI, const int* __restrict__ idxI,
    const int* __restrict__ cnt,
    const unsigned short* __restrict__ BpU, const unsigned short* __restrict__ BpI,
    const float* __restrict__ blU, const float* __restrict__ blI,
    const float* __restrict__ gU, const float* __restrict__ beU,
    const float* __restrict__ gI, const float* __restrict__ beI,
    float* __restrict__ xh) {
  __shared__ __align__(16) char Abuf[32 * 512];
  __shared__ float preLN[32][132];
  __shared__ float stat[32][2];
  int t = threadIdx.x, wave = t >> 6, lane = t & 63;
  int row0 = blockIdx.x * 32;
  bool isU = row0 < NUQ;
  const int* off = isU ? offU : offI;
  const int* idx = isU ? idxU : idxI;
  int dBase = isU ? 0 : NUQ;
  int sBase = isU ? NUQ : 0;   // users gather from item rows and vice versa
  const unsigned short* Bp = isU ? BpU : BpI;
  const float* bl = isU ? blU : blI;
  const float* g  = isU ? gU : gI;
  const float* be = isU ? beU : beI;

  // stage: wave w owns rows w*8 .. w*8+7 (mean -> chunks 0..15, own y -> 16..31)
  for (int r8 = 0; r8 < 8; ++r8) {
    int r = wave * 8 + r8;
    int d = row0 + r;
    int e0 = off[d - dBase], e1 = off[d - dBase + 1];
    float sx = 0.f, sy = 0.f, tx = 0.f, ty = 0.f;
    int e = e0;
    for (; e + 2 <= e1; e += 2) {
      unsigned u0 = *reinterpret_cast<const unsigned*>(&y_bf[(size_t)(sBase + idx[e]) * CC + lane * 2]);
      unsigned u1 = *reinterpret_cast<const unsigned*>(&y_bf[(size_t)(sBase + idx[e + 1]) * CC + lane * 2]);
      sx += bflo(u0); sy += bfhi(u0); tx += bflo(u1); ty += bfhi(u1);
    }
    if (e < e1) {
      unsigned u0 = *reinterpret_cast<const unsigned*>(&y_bf[(size_t)(sBase + idx[e]) * CC + lane * 2]);
      sx += bflo(u0); sy += bfhi(u0);
    }
    sx += tx; sy += ty;
    float inv = 1.0f / fmaxf((float)cnt[d], 1.0f);
    unsigned pm = (unsigned)f2bf(sx * inv) | ((unsigned)f2bf(sy * inv) << 16);
    int chunk = (lane >> 2) ^ (r & 7);
    *reinterpret_cast<unsigned*>(Abuf + r * 512 + chunk * 16 + (lane & 3) * 4) = pm;
    unsigned pv = *reinterpret_cast<const unsigned*>(&y_bf[(size_t)(row0 + r) * CC + lane * 2]);
    int chunk2 = (16 + (lane >> 2)) ^ (r & 7);
    *reinterpret_cast<unsigned*>(Abuf + r * 512 + chunk2 * 16 + (lane & 3) * 4) = pv;
  }
  __syncthreads();
  // MFMA: K=256 over [mean | y], B = [Wl; Wr] prepacked
  int rt = wave & 1, ctb = (wave >> 1) * 4;
  f32x4 acc0 = {0.f, 0.f, 0.f, 0.f}, acc1 = acc0, acc2 = acc0, acc3 = acc0;
  int arow = rt * 16 + (lane & 15);
  const char* abase = Abuf + arow * 512;
  int axor = arow & 7;
  const bf16x8* bp0 = reinterpret_cast<const bf16x8*>(Bp);
  for (int kk = 0; kk < 8; ++kk) {
    bf16x8 a = *reinterpret_cast<const bf16x8*>(abase + (((kk * 4 + (lane >> 4)) ^ axor) * 16));
    const bf16x8* bp = bp0 + (size_t)kk * 64 + lane;
    acc0 = __builtin_amdgcn_mfma_f32_16x16x32_bf16(a, bp[(size_t)(ctb + 0) * 8 * 64], acc0, 0, 0, 0);
    acc1 = __builtin_amdgcn_mfma_f32_16x16x32_bf16(a, bp[(size_t)(ctb + 1) * 8 * 64], acc1, 0, 0, 0);
    acc2 = __builtin_amdgcn_mfma_f32_16x16x32_bf16(a, bp[(size_t)(ctb + 2) * 8 * 64], acc2, 0, 0, 0);
    acc3 = __builtin_amdgcn_mfma_f32_16x16x32_bf16(a, bp[(size_t)(ctb + 3) * 8 * 64], acc3, 0, 0, 0);
  }
  // epilogue: bias -> preLN (padded stride 132 -> conflict-free)
  {
    int prow = rt * 16 + ((lane >> 4) << 2);
    int c0 = ctb * 16 + (lane & 15);
    float b0 = bl[c0], b1 = bl[c0 + 16], b2 = bl[c0 + 32], b3 = bl[c0 + 48];
#pragma unroll
    for (int q = 0; q < 4; ++q) {
      preLN[prow + q][c0]      = acc0[q] + b0;
      preLN[prow + q][c0 + 16] = acc1[q] + b1;
      preLN[prow + q][c0 + 32] = acc2[q] + b2;
      preLN[prow + q][c0 + 48] = acc3[q] + b3;
    }
  }
  __syncthreads();
  // LN stats: 8 threads per row
  {
    int rr = t >> 3, j = t & 7;
    float s = 0.f, sq = 0.f;
#pragma unroll
    for (int i = 0; i < 16; ++i) { float v = preLN[rr][j + 8 * i]; s += v; sq += v * v; }
    s += __shfl_xor(s, 1); sq += __shfl_xor(sq, 1);
    s += __shfl_xor(s, 2); sq += __shfl_xor(sq, 2);
    s += __shfl_xor(s, 4); sq += __shfl_xor(sq, 4);
    if (j == 0) {
      float mu = s * (1.0f / CC);
      float var = sq * (1.0f / CC) - mu * mu;
      stat[rr][0] = mu;
      stat[rr][1] = rsqrtf(var + 1e-5f);
    }
  }
  __syncthreads();
  for (int i = t; i < 32 * CC; i += 256) {
    int r = i >> 7, c = i & 127;
    float v = (preLN[r][c] - stat[r][0]) * stat[r][1] * g[c] + be[c];
    xh[(size_t)(row0 + r) * CC + c] = fmaxf(v, 0.f);
  }
}

extern "C" void kernel_launch(void* const* d_in, const int* in_sizes, int n_in,
                              void* d_out, int out_size, void* d_ws, size_t ws_size,
                              hipStream_t stream) {
  const float* x_user = (const float*)d_in[0];
  const float* x_item = (const float*)d_in[1];
  const float* PE     = (const float*)d_in[2];
  const float* sui_Wl = (const float*)d_in[3];
  const float* sui_bl = (const float*)d_in[4];
  const float* sui_Wr = (const float*)d_in[5];
  const float* siu_Wl = (const float*)d_in[6];
  const float* siu_bl = (const float*)d_in[7];
  const float* siu_Wr = (const float*)d_in[8];
  const float* lnu_g  = (const float*)d_in[9];
  const float* lnu_b  = (const float*)d_in[10];
  const float* lni_g  = (const float*)d_in[11];
  const float* lni_b  = (const float*)d_in[12];
  const float* phi_eps = (const float*)d_in[13];
  const float* phi_W1  = (const float*)d_in[14];
  const float* phi_b1  = (const float*)d_in[15];
  const float* phi_W2  = (const float*)d_in[16];
  const float* phi_b2  = (const float*)d_in[17];
  const float* pe_W    = (const float*)d_in[18];
  const float* pe_b    = (const float*)d_in[19];
  const int* edge_ui   = (const int*)d_in[20];
  const int* edge_iu   = (const int*)d_in[21];
  const int* edge_hom  = (const int*)d_in[22];

  float* xh = (float*)d_out;                                    // [NH][C] f32
  float* agg = (float*)d_ws;                                    // [NH][PD] f32
  unsigned short* y_bf   = (unsigned short*)(agg + (size_t)NHN * PDM);   // [NH][C] bf16
  unsigned short* pel_bf = y_bf + (size_t)NHN * CC;             // [NH][PD] bf16
  unsigned short* pe_bf  = pel_bf + (size_t)NHN * PDM;          // [NH][PD] bf16
  int* ip = (int*)(pe_bf + (size_t)NHN * PDM);
  int* cnt      = ip;             ip += NHN;        // het in-degree (hom ids)
  int* cnt_hom  = ip;             ip += NHN;
  int* off_iu   = ip;             ip += NUQ + 1;    // users' in-edges (from items)
  int* off_ui   = ip;             ip += NIQ + 1;    // items' in-edges (from users)
  int* off_hom  = ip;             ip += NHN + 1;
  int* idx_ui   = ip;             ip += EHET;
  int* idx_iu   = ip;             ip += EHET;
  int* idx_hom  = ip;             ip += EHOM;
  int* cur_u    = ip;             ip += NUQ;
  int* cur_i    = ip;             ip += NIQ;
  int* cur_h    = ip;             ip += NHN;
  int* blksum   = ip;             ip += 256;
  int* blkoff   = ip;             ip += 257;
  unsigned short* packs = (unsigned short*)((((size_t)(ip)) + 15) & ~(size_t)15);
  unsigned short* sageP = packs;                    // [L][2 types] x 32768
  unsigned short* peP   = sageP + 4 * 32768;        // [L] x 24576
  unsigned short* g1P   = peP + 2 * 24576;          // [L] x 8192
  unsigned short* g2P   = g1P + 2 * 8192;           // [L] x 8192

  hipMemsetAsync(cnt, 0, NHN * sizeof(int), stream);
  hipMemsetAsync(cnt_hom, 0, NHN * sizeof(int), stream);
  hipMemsetAsync(cur_u, 0, NUQ * sizeof(int), stream);
  hipMemsetAsync(cur_i, 0, NIQ * sizeof(int), stream);
  hipMemsetAsync(cur_h, 0, NHN * sizeof(int), stream);

  k_count<<<(2 * EHET + 255) / 256, 256, 0, stream>>>(edge_ui + EHET, edge_iu + EHET, cnt);
  k_hist<<<(EHOM + 255) / 256, 256, 0, stream>>>(edge_hom + EHOM, EHOM, cnt_hom);
  k_pe2bf<<<(NHN * PDM / 2 + 255) / 256, 256, 0, stream>>>(PE, (unsigned*)pe_bf);

  {
    int n = NUQ, nb = (n + SCAN_CHUNK - 1) / SCAN_CHUNK;
    k_scan1<<<nb, 256, 0, stream>>>(cnt, n, off_iu, blksum);
    k_scan2<<<1, 256, 0, stream>>>(blksum, nb, blkoff);
    k_scan3<<<(n + 256) / 256 + 1, 256, 0, stream>>>(off_iu, n, blkoff, nb);
  }
  {
    int n = NIQ, nb = (n + SCAN_CHUNK - 1) / SCAN_CHUNK;
    k_scan1<<<nb, 256, 0, stream>>>(cnt + NUQ, n, off_ui, blksum);
    k_scan2<<<1, 256, 0, stream>>>(blksum, nb, blkoff);
    k_scan3<<<(n + 256) / 256 + 1, 256, 0, stream>>>(off_ui, n, blkoff, nb);
  }
  {
    int n = NHN, nb = (n + SCAN_CHUNK - 1) / SCAN_CHUNK;
    k_scan1<<<nb, 256, 0, stream>>>(cnt_hom, n, off_hom, blksum);
    k_scan2<<<1, 256, 0, stream>>>(blksum, nb, blkoff);
    k_scan3<<<(n + 256) / 256 + 1, 256, 0, stream>>>(off_hom, n, blkoff, nb);
  }
  k_fill<<<(EHET + 255) / 256, 256, 0, stream>>>(edge_ui, edge_ui + EHET, EHET, off_ui, cur_i, idx_ui);
  k_fill<<<(EHET + 255) / 256, 256, 0, stream>>>(edge_iu, edge_iu + EHET, EHET, off_iu, cur_u, idx_iu);
  k_fill<<<(EHOM + 255) / 256, 256, 0, stream>>>(edge_hom, edge_hom + EHOM, EHOM, off_hom, cur_h, idx_hom);

  k_aggcsr<<<NHN / 8, 256, 0, stream>>>(off_hom, idx_hom, pe_bf, agg);

  // weight prepack (bf16 fragment order)
  for (int l = 0; l < 2; ++l) {
    k_pack<<<64, 256, 0, stream>>>(siu_Wl + (size_t)l * CC * CC, CC, 128, 0, 8, sageP + (size_t)(l * 2) * 32768);
    k_pack<<<64, 256, 0, stream>>>(siu_Wr + (size_t)l * CC * CC, CC, 128, 4, 8, sageP + (size_t)(l * 2) * 32768);
    k_pack<<<64, 256, 0, stream>>>(sui_Wl + (size_t)l * CC * CC, CC, 128, 0, 8, sageP + (size_t)(l * 2 + 1) * 32768);
    k_pack<<<64, 256, 0, stream>>>(sui_Wr + (size_t)l * CC * CC, CC, 128, 4, 8, sageP + (size_t)(l * 2 + 1) * 32768);
    k_pack<<<96, 256, 0, stream>>>(pe_W + (size_t)l * (CC + PDM) * CC, CC + PDM, 128, 0, 6, peP + (size_t)l * 24576);
    k_pack<<<32, 256, 0, stream>>>(phi_W1 + (size_t)l * PDM * PHM, PDM, 128, 0, 2, g1P + (size_t)l * 8192);
    k_pack<<<32, 256, 0, stream>>>(phi_W2 + (size_t)l * PHM * PDM, PHM, 64, 0, 4, g2P + (size_t)l * 8192);
  }

  for (int l = 0; l < 2; ++l) {
    const float* xu_eff = (l == 0) ? x_user : xh;
    const float* xi_eff = (l == 0) ? x_item : xh + (size_t)NUQ * CC;
    k_gin_mfma<<<NHN / 32, 256, 0, stream>>>(PE, agg,
        g1P + (size_t)l * 8192, phi_b1 + (size_t)l * PHM,
        g2P + (size_t)l * 8192, phi_b2 + (size_t)l * PDM,
        phi_eps + l, pel_bf);
    k_peproj_mfma<<<NHN / 32, 256, 0, stream>>>(xu_eff, xi_eff, pel_bf,
        peP + (size_t)l * 24576, pe_b + (size_t)l * CC, y_bf);
    k_sage_mfma<<<NHN / 32, 256, 0, stream>>>(y_bf,
        off_iu, idx_iu, off_ui, idx_ui, cnt,
        sageP + (size_t)(l * 2) * 32768, sageP + (size_t)(l * 2 + 1) * 32768,
        siu_bl + (size_t)l * CC, sui_bl + (size_t)l * CC,
        lnu_g + (size_t)l * CC, lnu_b + (size_t)l * CC,
        lni_g + (size_t)l * CC, lni_b + (size_t)l * CC, xh);
  }
}

// Round 5
// 739.325 us; speedup vs baseline: 3.4768x; 1.1566x over previous
//
#include <hip/hip_runtime.h>

#define NUQ 100000
#define NIQ 100000
#define NHN 200000
#define CC 128
#define PDM 64
#define PHM 128
#define EHET 500000
#define EHOM 1000000
#define SCAN_CHUNK 2048

typedef __attribute__((ext_vector_type(8))) short bf16x8;
typedef __attribute__((ext_vector_type(4))) float f32x4;

__device__ inline unsigned short f2bf(float x) {
  union { float f; unsigned u; } c; c.f = x;
  unsigned r = c.u + 0x7FFF + ((c.u >> 16) & 1);
  return (unsigned short)(r >> 16);
}
__device__ inline float bflo(unsigned u) { union { unsigned u; float f; } c; c.u = u << 16; return c.f; }
__device__ inline float bfhi(unsigned u) { union { unsigned u; float f; } c; c.u = u & 0xffff0000u; return c.f; }

// ---------- het in-degree counts (combined hom-id space) ----------
__global__ void k_count(const int* __restrict__ eui_dst, const int* __restrict__ eiu_dst,
                        int* __restrict__ cnt) {
  int i = blockIdx.x * 256 + threadIdx.x;
  if (i < EHET) {
    atomicAdd(&cnt[NUQ + eui_dst[i]], 1);          // items
  } else if (i < 2 * EHET) {
    atomicAdd(&cnt[eiu_dst[i - EHET]], 1);         // users
  }
}

__global__ void k_hist(const int* __restrict__ dst, int E, int* __restrict__ cnt) {
  int e = blockIdx.x * 256 + threadIdx.x;
  if (e < E) atomicAdd(&cnt[dst[e]], 1);
}

// ---------- 3-kernel exclusive scan ----------
__global__ __launch_bounds__(256) void k_scan1(const int* __restrict__ in, int n,
                                               int* __restrict__ out, int* __restrict__ blksum) {
  __shared__ int sh[256];
  int b = blockIdx.x, t = threadIdx.x;
  int base = b * SCAN_CHUNK + t * 8;
  int v[8]; int s = 0;
#pragma unroll
  for (int i = 0; i < 8; ++i) {
    int x = (base + i < n) ? in[base + i] : 0;
    v[i] = s;
    s += x;
  }
  sh[t] = s; __syncthreads();
  for (int d = 1; d < 256; d <<= 1) {
    int x = (t >= d) ? sh[t - d] : 0;
    __syncthreads();
    sh[t] += x;
    __syncthreads();
  }
  int texcl = sh[t] - s;
#pragma unroll
  for (int i = 0; i < 8; ++i)
    if (base + i < n) out[base + i] = texcl + v[i];
  if (t == 255) blksum[b] = sh[255];
}

__global__ void k_scan2(const int* __restrict__ blksum, int nb, int* __restrict__ blkoff) {
  __shared__ int sh[256];
  int t = threadIdx.x;
  int x0 = (t < nb) ? blksum[t] : 0;
  sh[t] = x0; __syncthreads();
  for (int d = 1; d < 256; d <<= 1) {
    int x = (t >= d) ? sh[t - d] : 0;
    __syncthreads();
    sh[t] += x;
    __syncthreads();
  }
  if (t < nb) blkoff[t] = sh[t] - x0;
  if (t == 0) blkoff[nb] = sh[255];
}

__global__ void k_scan3(int* __restrict__ off, int n, const int* __restrict__ blkoff, int nb) {
  int i = blockIdx.x * 256 + threadIdx.x;
  if (i < n) off[i] += blkoff[i >> 11];
  else if (i == n) off[n] = blkoff[nb];
}

// ---------- CSR fill via atomic cursor ----------
__global__ void k_fill(const int* __restrict__ src, const int* __restrict__ dst, int E,
                       const int* __restrict__ off, int* __restrict__ cur, int* __restrict__ out) {
  int e = blockIdx.x * 256 + threadIdx.x;
  if (e < E) {
    int d = dst[e];
    int p = atomicAdd(&cur[d], 1);
    out[off[d] + p] = src[e];
  }
}

// ---------- PE -> bf16 copy ----------
__global__ __launch_bounds__(256) void k_pe2bf(const float* __restrict__ pe,
                                               unsigned* __restrict__ out) {
  int i = blockIdx.x * 256 + threadIdx.x;
  if (i < NHN * PDM / 2) {
    float2 v = *reinterpret_cast<const float2*>(&pe[(size_t)i * 2]);
    out[i] = (unsigned)f2bf(v.x) | ((unsigned)f2bf(v.y) << 16);
  }
}

// ---------- GIN neighborhood sum via CSR gather (16 lanes per node, uint2 loads) ----------
__global__ __launch_bounds__(256) void k_aggcsr(const int* __restrict__ off, const int* __restrict__ idx,
                                                const unsigned short* __restrict__ pe_bf,
                                                float* __restrict__ agg) {
  int q = threadIdx.x >> 4, ql = threadIdx.x & 15;
  int n = blockIdx.x * 16 + q;
  int e0 = off[n], e1 = off[n + 1];
  float s0 = 0.f, s1 = 0.f, s2 = 0.f, s3 = 0.f;
  float t0 = 0.f, t1 = 0.f, t2 = 0.f, t3 = 0.f;
  int e = e0;
  for (; e + 2 <= e1; e += 2) {
    uint2 u = *reinterpret_cast<const uint2*>(&pe_bf[(size_t)idx[e] * PDM + ql * 4]);
    uint2 v = *reinterpret_cast<const uint2*>(&pe_bf[(size_t)idx[e + 1] * PDM + ql * 4]);
    s0 += bflo(u.x); s1 += bfhi(u.x); s2 += bflo(u.y); s3 += bfhi(u.y);
    t0 += bflo(v.x); t1 += bfhi(v.x); t2 += bflo(v.y); t3 += bfhi(v.y);
  }
  if (e < e1) {
    uint2 u = *reinterpret_cast<const uint2*>(&pe_bf[(size_t)idx[e] * PDM + ql * 4]);
    s0 += bflo(u.x); s1 += bfhi(u.x); s2 += bflo(u.y); s3 += bfhi(u.y);
  }
  float4 o = { s0 + t0, s1 + t1, s2 + t2, s3 + t3 };
  *reinterpret_cast<float4*>(&agg[(size_t)n * PDM + ql * 4]) = o;
}

// ---------- pack f32 weights (Ksub x NC) into MFMA B-fragment order (bf16) ----------
// lane l holds B[k = kk*32 + 8*(l>>4) + j][col = ct*16 + (l&15)], j=0..7 contiguous 16B
__global__ void k_pack(const float* __restrict__ W, int Ksub, int NC, int kkBase, int KKtot,
                       unsigned short* __restrict__ out) {
  int i = blockIdx.x * 256 + threadIdx.x;
  if (i < Ksub * NC) {
    int k = i / NC, n = i % NC;
    int kk = kkBase + (k >> 5);
    int lane = (n & 15) + (((k >> 3) & 3) << 4);
    int j = k & 7;
    int o16 = ((n >> 4) * KKtot + kk) * 64 + lane;
    out[o16 * 8 + j] = f2bf(W[i]);
  }
}

// ---------- fused GIN MLP via MFMA: pe_l = relu(h@W1+b1)@W2+b2 (bf16 out) ----------
__global__ __launch_bounds__(256) void k_gin_mfma(
    const float* __restrict__ pe, const float* __restrict__ agg,
    const unsigned short* __restrict__ B1p, const float* __restrict__ b1,
    const unsigned short* __restrict__ B2p, const float* __restrict__ b2,
    const float* __restrict__ eps_p, unsigned short* __restrict__ pel) {
  __shared__ __align__(16) char Ah[32 * 128];
  __shared__ __align__(16) char Hh[32 * 256];
  int t = threadIdx.x, wave = t >> 6, lane = t & 63;
  int row0 = blockIdx.x * 32;
  float e1 = 1.0f + eps_p[0];
  for (int i = t; i < 32 * 32; i += 256) {
    int r = i >> 5, cp = i & 31;
    float2 p2 = *reinterpret_cast<const float2*>(&pe[(size_t)(row0 + r) * PDM + cp * 2]);
    float2 a2 = *reinterpret_cast<const float2*>(&agg[(size_t)(row0 + r) * PDM + cp * 2]);
    unsigned pv = (unsigned)f2bf(e1 * p2.x + a2.x) | ((unsigned)f2bf(e1 * p2.y + a2.y) << 16);
    int chunk = (cp >> 2) ^ (r & 7);
    *reinterpret_cast<unsigned*>(Ah + r * 128 + chunk * 16 + (cp & 3) * 4) = pv;
  }
  __syncthreads();
  int rt = wave & 1, ctb = (wave >> 1) * 4;
  int arow = rt * 16 + (lane & 15);
  int axor = arow & 7;
  // GEMM1: [32x64] @ [64x128]
  {
    f32x4 acc0 = {0.f, 0.f, 0.f, 0.f}, acc1 = acc0, acc2 = acc0, acc3 = acc0;
    const char* abase = Ah + arow * 128;
    const bf16x8* bv = reinterpret_cast<const bf16x8*>(B1p);
    for (int kk = 0; kk < 2; ++kk) {
      bf16x8 a = *reinterpret_cast<const bf16x8*>(abase + (((kk * 4 + (lane >> 4)) ^ axor) * 16));
      const bf16x8* bp = bv + (size_t)kk * 64 + lane;
      acc0 = __builtin_amdgcn_mfma_f32_16x16x32_bf16(a, bp[(size_t)(ctb + 0) * 2 * 64], acc0, 0, 0, 0);
      acc1 = __builtin_amdgcn_mfma_f32_16x16x32_bf16(a, bp[(size_t)(ctb + 1) * 2 * 64], acc1, 0, 0, 0);
      acc2 = __builtin_amdgcn_mfma_f32_16x16x32_bf16(a, bp[(size_t)(ctb + 2) * 2 * 64], acc2, 0, 0, 0);
      acc3 = __builtin_amdgcn_mfma_f32_16x16x32_bf16(a, bp[(size_t)(ctb + 3) * 2 * 64], acc3, 0, 0, 0);
    }
    int prow = rt * 16 + ((lane >> 4) << 2);
    int c0 = ctb * 16 + (lane & 15);
    float bb0 = b1[c0], bb1 = b1[c0 + 16], bb2 = b1[c0 + 32], bb3 = b1[c0 + 48];
    int j2 = (c0 & 7) * 2, cb = c0 >> 3;
#pragma unroll
    for (int q = 0; q < 4; ++q) {
      int rw = prow + q, rx = rw & 7;
      char* hb = Hh + rw * 256;
      *reinterpret_cast<unsigned short*>(hb + (((cb + 0) ^ rx) * 16) + j2) = f2bf(fmaxf(acc0[q] + bb0, 0.f));
      *reinterpret_cast<unsigned short*>(hb + (((cb + 2) ^ rx) * 16) + j2) = f2bf(fmaxf(acc1[q] + bb1, 0.f));
      *reinterpret_cast<unsigned short*>(hb + (((cb + 4) ^ rx) * 16) + j2) = f2bf(fmaxf(acc2[q] + bb2, 0.f));
      *reinterpret_cast<unsigned short*>(hb + (((cb + 6) ^ rx) * 16) + j2) = f2bf(fmaxf(acc3[q] + bb3, 0.f));
    }
  }
  __syncthreads();
  // GEMM2: [32x128] @ [128x64]
  {
    int ct2 = (wave >> 1) * 2;
    f32x4 d0 = {0.f, 0.f, 0.f, 0.f}, d1 = d0;
    const char* hbase = Hh + arow * 256;
    const bf16x8* bv = reinterpret_cast<const bf16x8*>(B2p);
    for (int kk = 0; kk < 4; ++kk) {
      bf16x8 a = *reinterpret_cast<const bf16x8*>(hbase + (((kk * 4 + (lane >> 4)) ^ axor) * 16));
      const bf16x8* bp = bv + (size_t)kk * 64 + lane;
      d0 = __builtin_amdgcn_mfma_f32_16x16x32_bf16(a, bp[(size_t)(ct2 + 0) * 4 * 64], d0, 0, 0, 0);
      d1 = __builtin_amdgcn_mfma_f32_16x16x32_bf16(a, bp[(size_t)(ct2 + 1) * 4 * 64], d1, 0, 0, 0);
    }
    int prow0 = row0 + rt * 16 + ((lane >> 4) << 2);
    int c0 = ct2 * 16 + (lane & 15);
    float bb0 = b2[c0], bb1 = b2[c0 + 16];
#pragma unroll
    for (int q = 0; q < 4; ++q) {
      pel[(size_t)(prow0 + q) * PDM + c0] = f2bf(d0[q] + bb0);
      pel[(size_t)(prow0 + q) * PDM + c0 + 16] = f2bf(d1[q] + bb1);
    }
  }
}

// ---------- peproj: y = concat(x, pe_l) @ pe_W + pe_b  (K=192, bf16 MFMA, bf16 out) ----------
__global__ __launch_bounds__(256) void k_peproj_mfma(
    const float* __restrict__ xu, const float* __restrict__ xi,
    const unsigned short* __restrict__ pel,
    const unsigned short* __restrict__ Bp, const float* __restrict__ bias,
    unsigned short* __restrict__ y_bf) {
  __shared__ __align__(16) char Abuf[32 * 384];
  int t = threadIdx.x, wave = t >> 6, lane = t & 63;
  int row0 = blockIdx.x * 32;
  const float* xs = (row0 < NUQ) ? xu : xi;
  int rbase = (row0 < NUQ) ? row0 : row0 - NUQ;
  // stage x (cols 0..127 -> chunks 0..15), f32 -> bf16, XOR-swizzled
  for (int i = t; i < 32 * 64; i += 256) {
    int r = i >> 6, cp = i & 63;
    float2 v = *reinterpret_cast<const float2*>(&xs[(size_t)(rbase + r) * CC + cp * 2]);
    unsigned pv = (unsigned)f2bf(v.x) | ((unsigned)f2bf(v.y) << 16);
    int chunk = (cp >> 2) ^ (r & 7);
    *reinterpret_cast<unsigned*>(Abuf + r * 384 + chunk * 16 + (cp & 3) * 4) = pv;
  }
  // stage pe_l (bf16, raw copy -> chunks 16..23)
  for (int i = t; i < 32 * 32; i += 256) {
    int r = i >> 5, cp = i & 31;
    unsigned pv = *reinterpret_cast<const unsigned*>(&pel[(size_t)(row0 + r) * PDM + cp * 2]);
    int chunk = (16 + (cp >> 2)) ^ (r & 7);
    *reinterpret_cast<unsigned*>(Abuf + r * 384 + chunk * 16 + (cp & 3) * 4) = pv;
  }
  __syncthreads();
  int rt = wave & 1, ctb = (wave >> 1) * 4;
  f32x4 acc0 = {0.f, 0.f, 0.f, 0.f}, acc1 = acc0, acc2 = acc0, acc3 = acc0;
  int arow = rt * 16 + (lane & 15);
  const char* abase = Abuf + arow * 384;
  int axor = arow & 7;
  const bf16x8* bp0 = reinterpret_cast<const bf16x8*>(Bp);
  for (int kk = 0; kk < 6; ++kk) {
    bf16x8 a = *reinterpret_cast<const bf16x8*>(abase + (((kk * 4 + (lane >> 4)) ^ axor) * 16));
    const bf16x8* bp = bp0 + (size_t)kk * 64 + lane;
    acc0 = __builtin_amdgcn_mfma_f32_16x16x32_bf16(a, bp[(size_t)(ctb + 0) * 6 * 64], acc0, 0, 0, 0);
    acc1 = __builtin_amdgcn_mfma_f32_16x16x32_bf16(a, bp[(size_t)(ctb + 1) * 6 * 64], acc1, 0, 0, 0);
    acc2 = __builtin_amdgcn_mfma_f32_16x16x32_bf16(a, bp[(size_t)(ctb + 2) * 6 * 64], acc2, 0, 0, 0);
    acc3 = __builtin_amdgcn_mfma_f32_16x16x32_bf16(a, bp[(size_t)(ctb + 3) * 6 * 64], acc3, 0, 0, 0);
  }
  int prow0 = row0 + rt * 16 + ((lane >> 4) << 2);
  int c0 = ctb * 16 + (lane & 15);
  float b0 = bias[c0], b1 = bias[c0 + 16], b2 = bias[c0 + 32], b3 = bias[c0 + 48];
#pragma unroll
  for (int q = 0; q < 4; ++q) {
    size_t rb = (size_t)(prow0 + q) * CC;
    y_bf[rb + c0]      = f2bf(acc0[q] + b0);
    y_bf[rb + c0 + 16] = f2bf(acc1[q] + b1);
    y_bf[rb + c0 + 32] = f2bf(acc2[q] + b2);
    y_bf[rb + c0 + 48] = f2bf(acc3[q] + b3);
  }
}

// ---------- fused: CSR mean-gather (bf16 y, dual-row) + dual GEMM (K=256) + LN + ReLU ----------
__global__ __launch_bounds__(256) void k_sage_mfma(
    const unsigned short* __restrict__ y_bf,
    const int* __restrict__ offU, const int* __restrict__ idxU,
    const int* __restrict__ offI, const int* __restrict__ idxI,
    const int* __restrict__ cnt,
    const unsigned short* __restrict__ BpU, const unsigned short* __restrict__ BpI,
    const float* __restrict__ blU, const float* __restrict__ blI,
    const float* __restrict__ gU, const float* __restrict__ beU,
    const float* __restrict__ gI, const float* __restrict__ beI,
    float* __restrict__ xh) {
  // LDS union: Abuf (16384 B) is dead after the MFMA loop; preLN reuses it.
  __shared__ __align__(16) char U[32 * 132 * 4 + 32 * 8];
  char* Abuf = U;
  float (*preLN)[132] = reinterpret_cast<float (*)[132]>(U);
  float (*stat)[2] = reinterpret_cast<float (*)[2]>(U + 32 * 132 * 4);
  int t = threadIdx.x, wave = t >> 6, lane = t & 63;
  int row0 = blockIdx.x * 32;
  bool isU = row0 < NUQ;
  const int* off = isU ? offU : offI;
  const int* idx = isU ? idxU : idxI;
  int dBase = isU ? 0 : NUQ;
  int sBase = isU ? NUQ : 0;   // users gather from item rows and vice versa
  const unsigned short* Bp = isU ? BpU : BpI;
  const float* bl = isU ? blU : blI;
  const float* g  = isU ? gU : gI;
  const float* be = isU ? beU : beI;

  // stage: wave w owns rows w*8..w*8+7, processed as 4 dual-row pairs
  // (lanes 0..31 -> even row, lanes 32..63 -> odd row; 8 B/lane covers 256 B row)
  int half = lane >> 5, hl = lane & 31;
  for (int pr = 0; pr < 4; ++pr) {
    int r = wave * 8 + pr * 2 + half;
    int d = row0 + r;
    int e0 = off[d - dBase], e1 = off[d - dBase + 1];
    float s0 = 0.f, s1 = 0.f, s2 = 0.f, s3 = 0.f;
    float t0 = 0.f, t1 = 0.f, t2 = 0.f, t3 = 0.f;
    int e = e0;
    for (; e + 2 <= e1; e += 2) {
      uint2 u = *reinterpret_cast<const uint2*>(&y_bf[(size_t)(sBase + idx[e]) * CC + hl * 4]);
      uint2 v = *reinterpret_cast<const uint2*>(&y_bf[(size_t)(sBase + idx[e + 1]) * CC + hl * 4]);
      s0 += bflo(u.x); s1 += bfhi(u.x); s2 += bflo(u.y); s3 += bfhi(u.y);
      t0 += bflo(v.x); t1 += bfhi(v.x); t2 += bflo(v.y); t3 += bfhi(v.y);
    }
    if (e < e1) {
      uint2 u = *reinterpret_cast<const uint2*>(&y_bf[(size_t)(sBase + idx[e]) * CC + hl * 4]);
      s0 += bflo(u.x); s1 += bfhi(u.x); s2 += bflo(u.y); s3 += bfhi(u.y);
    }
    s0 += t0; s1 += t1; s2 += t2; s3 += t3;
    float inv = 1.0f / fmaxf((float)cnt[d], 1.0f);
    int cp0 = hl * 2;  // first col-pair this lane covers (cp0, cp0+1 share a chunk)
    uint2 pm;
    pm.x = (unsigned)f2bf(s0 * inv) | ((unsigned)f2bf(s1 * inv) << 16);
    pm.y = (unsigned)f2bf(s2 * inv) | ((unsigned)f2bf(s3 * inv) << 16);
    int chunk = (cp0 >> 2) ^ (r & 7);
    *reinterpret_cast<uint2*>(Abuf + r * 512 + chunk * 16 + (cp0 & 3) * 4) = pm;
    uint2 pv = *reinterpret_cast<const uint2*>(&y_bf[(size_t)(row0 + r) * CC + hl * 4]);
    int chunk2 = (16 + (cp0 >> 2)) ^ (r & 7);
    *reinterpret_cast<uint2*>(Abuf + r * 512 + chunk2 * 16 + (cp0 & 3) * 4) = pv;
  }
  __syncthreads();
  // MFMA: K=256 over [mean | y], B = [Wl; Wr] prepacked
  int rt = wave & 1, ctb = (wave >> 1) * 4;
  f32x4 acc0 = {0.f, 0.f, 0.f, 0.f}, acc1 = acc0, acc2 = acc0, acc3 = acc0;
  int arow = rt * 16 + (lane & 15);
  const char* abase = Abuf + arow * 512;
  int axor = arow & 7;
  const bf16x8* bp0 = reinterpret_cast<const bf16x8*>(Bp);
  for (int kk = 0; kk < 8; ++kk) {
    bf16x8 a = *reinterpret_cast<const bf16x8*>(abase + (((kk * 4 + (lane >> 4)) ^ axor) * 16));
    const bf16x8* bp = bp0 + (size_t)kk * 64 + lane;
    acc0 = __builtin_amdgcn_mfma_f32_16x16x32_bf16(a, bp[(size_t)(ctb + 0) * 8 * 64], acc0, 0, 0, 0);
    acc1 = __builtin_amdgcn_mfma_f32_16x16x32_bf16(a, bp[(size_t)(ctb + 1) * 8 * 64], acc1, 0, 0, 0);
    acc2 = __builtin_amdgcn_mfma_f32_16x16x32_bf16(a, bp[(size_t)(ctb + 2) * 8 * 64], acc2, 0, 0, 0);
    acc3 = __builtin_amdgcn_mfma_f32_16x16x32_bf16(a, bp[(size_t)(ctb + 3) * 8 * 64], acc3, 0, 0, 0);
  }
  __syncthreads();   // Abuf dead; preLN aliases it
  // epilogue: bias -> preLN (padded stride 132 -> conflict-free)
  {
    int prow = rt * 16 + ((lane >> 4) << 2);
    int c0 = ctb * 16 + (lane & 15);
    float b0 = bl[c0], b1 = bl[c0 + 16], b2 = bl[c0 + 32], b3 = bl[c0 + 48];
#pragma unroll
    for (int q = 0; q < 4; ++q) {
      preLN[prow + q][c0]      = acc0[q] + b0;
      preLN[prow + q][c0 + 16] = acc1[q] + b1;
      preLN[prow + q][c0 + 32] = acc2[q] + b2;
      preLN[prow + q][c0 + 48] = acc3[q] + b3;
    }
  }
  __syncthreads();
  // LN stats: 8 threads per row
  {
    int rr = t >> 3, j = t & 7;
    float s = 0.f, sq = 0.f;
#pragma unroll
    for (int i = 0; i < 16; ++i) { float v = preLN[rr][j + 8 * i]; s += v; sq += v * v; }
    s += __shfl_xor(s, 1); sq += __shfl_xor(sq, 1);
    s += __shfl_xor(s, 2); sq += __shfl_xor(sq, 2);
    s += __shfl_xor(s, 4); sq += __shfl_xor(sq, 4);
    if (j == 0) {
      float mu = s * (1.0f / CC);
      float var = sq * (1.0f / CC) - mu * mu;
      stat[rr][0] = mu;
      stat[rr][1] = rsqrtf(var + 1e-5f);
    }
  }
  __syncthreads();
  for (int i = t; i < 32 * CC; i += 256) {
    int r = i >> 7, c = i & 127;
    float v = (preLN[r][c] - stat[r][0]) * stat[r][1] * g[c] + be[c];
    xh[(size_t)(row0 + r) * CC + c] = fmaxf(v, 0.f);
  }
}

extern "C" void kernel_launch(void* const* d_in, const int* in_sizes, int n_in,
                              void* d_out, int out_size, void* d_ws, size_t ws_size,
                              hipStream_t stream) {
  const float* x_user = (const float*)d_in[0];
  const float* x_item = (const float*)d_in[1];
  const float* PE     = (const float*)d_in[2];
  const float* sui_Wl = (const float*)d_in[3];
  const float* sui_bl = (const float*)d_in[4];
  const float* sui_Wr = (const float*)d_in[5];
  const float* siu_Wl = (const float*)d_in[6];
  const float* siu_bl = (const float*)d_in[7];
  const float* siu_Wr = (const float*)d_in[8];
  const float* lnu_g  = (const float*)d_in[9];
  const float* lnu_b  = (const float*)d_in[10];
  const float* lni_g  = (const float*)d_in[11];
  const float* lni_b  = (const float*)d_in[12];
  const float* phi_eps = (const float*)d_in[13];
  const float* phi_W1  = (const float*)d_in[14];
  const float* phi_b1  = (const float*)d_in[15];
  const float* phi_W2  = (const float*)d_in[16];
  const float* phi_b2  = (const float*)d_in[17];
  const float* pe_W    = (const float*)d_in[18];
  const float* pe_b    = (const float*)d_in[19];
  const int* edge_ui   = (const int*)d_in[20];
  const int* edge_iu   = (const int*)d_in[21];
  const int* edge_hom  = (const int*)d_in[22];

  float* xh = (float*)d_out;                                    // [NH][C] f32
  float* agg = (float*)d_ws;                                    // [NH][PD] f32
  unsigned short* y_bf   = (unsigned short*)(agg + (size_t)NHN * PDM);   // [NH][C] bf16
  unsigned short* pel_bf = y_bf + (size_t)NHN * CC;             // [NH][PD] bf16
  unsigned short* pe_bf  = pel_bf + (size_t)NHN * PDM;          // [NH][PD] bf16
  int* ip = (int*)(pe_bf + (size_t)NHN * PDM);
  int* cnt      = ip;             ip += NHN;        // het in-degree (hom ids)
  int* cnt_hom  = ip;             ip += NHN;
  int* off_iu   = ip;             ip += NUQ + 1;    // users' in-edges (from items)
  int* off_ui   = ip;             ip += NIQ + 1;    // items' in-edges (from users)
  int* off_hom  = ip;             ip += NHN + 1;
  int* idx_ui   = ip;             ip += EHET;
  int* idx_iu   = ip;             ip += EHET;
  int* idx_hom  = ip;             ip += EHOM;
  int* cur_u    = ip;             ip += NUQ;
  int* cur_i    = ip;             ip += NIQ;
  int* cur_h    = ip;             ip += NHN;
  int* blksum   = ip;             ip += 256;
  int* blkoff   = ip;             ip += 257;
  unsigned short* packs = (unsigned short*)((((size_t)(ip)) + 15) & ~(size_t)15);
  unsigned short* sageP = packs;                    // [L][2 types] x 32768
  unsigned short* peP   = sageP + 4 * 32768;        // [L] x 24576
  unsigned short* g1P   = peP + 2 * 24576;          // [L] x 8192
  unsigned short* g2P   = g1P + 2 * 8192;           // [L] x 8192

  hipMemsetAsync(cnt, 0, NHN * sizeof(int), stream);
  hipMemsetAsync(cnt_hom, 0, NHN * sizeof(int), stream);
  hipMemsetAsync(cur_u, 0, NUQ * sizeof(int), stream);
  hipMemsetAsync(cur_i, 0, NIQ * sizeof(int), stream);
  hipMemsetAsync(cur_h, 0, NHN * sizeof(int), stream);

  k_count<<<(2 * EHET + 255) / 256, 256, 0, stream>>>(edge_ui + EHET, edge_iu + EHET, cnt);
  k_hist<<<(EHOM + 255) / 256, 256, 0, stream>>>(edge_hom + EHOM, EHOM, cnt_hom);
  k_pe2bf<<<(NHN * PDM / 2 + 255) / 256, 256, 0, stream>>>(PE, (unsigned*)pe_bf);

  {
    int n = NUQ, nb = (n + SCAN_CHUNK - 1) / SCAN_CHUNK;
    k_scan1<<<nb, 256, 0, stream>>>(cnt, n, off_iu, blksum);
    k_scan2<<<1, 256, 0, stream>>>(blksum, nb, blkoff);
    k_scan3<<<(n + 256) / 256 + 1, 256, 0, stream>>>(off_iu, n, blkoff, nb);
  }
  {
    int n = NIQ, nb = (n + SCAN_CHUNK - 1) / SCAN_CHUNK;
    k_scan1<<<nb, 256, 0, stream>>>(cnt + NUQ, n, off_ui, blksum);
    k_scan2<<<1, 256, 0, stream>>>(blksum, nb, blkoff);
    k_scan3<<<(n + 256) / 256 + 1, 256, 0, stream>>>(off_ui, n, blkoff, nb);
  }
  {
    int n = NHN, nb = (n + SCAN_CHUNK - 1) / SCAN_CHUNK;
    k_scan1<<<nb, 256, 0, stream>>>(cnt_hom, n, off_hom, blksum);
    k_scan2<<<1, 256, 0, stream>>>(blksum, nb, blkoff);
    k_scan3<<<(n + 256) / 256 + 1, 256, 0, stream>>>(off_hom, n, blkoff, nb);
  }
  k_fill<<<(EHET + 255) / 256, 256, 0, stream>>>(edge_ui, edge_ui + EHET, EHET, off_ui, cur_i, idx_ui);
  k_fill<<<(EHET + 255) / 256, 256, 0, stream>>>(edge_iu, edge_iu + EHET, EHET, off_iu, cur_u, idx_iu);
  k_fill<<<(EHOM + 255) / 256, 256, 0, stream>>>(edge_hom, edge_hom + EHOM, EHOM, off_hom, cur_h, idx_hom);

  k_aggcsr<<<NHN / 16, 256, 0, stream>>>(off_hom, idx_hom, pe_bf, agg);

  // weight prepack (bf16 fragment order)
  for (int l = 0; l < 2; ++l) {
    k_pack<<<64, 256, 0, stream>>>(siu_Wl + (size_t)l * CC * CC, CC, 128, 0, 8, sageP + (size_t)(l * 2) * 32768);
    k_pack<<<64, 256, 0, stream>>>(siu_Wr + (size_t)l * CC * CC, CC, 128, 4, 8, sageP + (size_t)(l * 2) * 32768);
    k_pack<<<64, 256, 0, stream>>>(sui_Wl + (size_t)l * CC * CC, CC, 128, 0, 8, sageP + (size_t)(l * 2 + 1) * 32768);
    k_pack<<<64, 256, 0, stream>>>(sui_Wr + (size_t)l * CC * CC, CC, 128, 4, 8, sageP + (size_t)(l * 2 + 1) * 32768);
    k_pack<<<96, 256, 0, stream>>>(pe_W + (size_t)l * (CC + PDM) * CC, CC + PDM, 128, 0, 6, peP + (size_t)l * 24576);
    k_pack<<<32, 256, 0, stream>>>(phi_W1 + (size_t)l * PDM * PHM, PDM, 128, 0, 2, g1P + (size_t)l * 8192);
    k_pack<<<32, 256, 0, stream>>>(phi_W2 + (size_t)l * PHM * PDM, PHM, 64, 0, 4, g2P + (size_t)l * 8192);
  }

  for (int l = 0; l < 2; ++l) {
    const float* xu_eff = (l == 0) ? x_user : xh;
    const float* xi_eff = (l == 0) ? x_item : xh + (size_t)NUQ * CC;
    k_gin_mfma<<<NHN / 32, 256, 0, stream>>>(PE, agg,
        g1P + (size_t)l * 8192, phi_b1 + (size_t)l * PHM,
        g2P + (size_t)l * 8192, phi_b2 + (size_t)l * PDM,
        phi_eps + l, pel_bf);
    k_peproj_mfma<<<NHN / 32, 256, 0, stream>>>(xu_eff, xi_eff, pel_bf,
        peP + (size_t)l * 24576, pe_b + (size_t)l * CC, y_bf);
    k_sage_mfma<<<NHN / 32, 256, 0, stream>>>(y_bf,
        off_iu, idx_iu, off_ui, idx_ui, cnt,
        sageP + (size_t)(l * 2) * 32768, sageP + (size_t)(l * 2 + 1) * 32768,
        siu_bl + (size_t)l * CC, sui_bl + (size_t)l * CC,
        lnu_g + (size_t)l * CC, lnu_b + (size_t)l * CC,
        lni_g + (size_t)l * CC, lni_b + (size_t)l * CC, xh);
  }
}

// Round 6
// 569.711 us; speedup vs baseline: 4.5119x; 1.2977x over previous
//
#include <hip/hip_runtime.h>

#define NUQ 100000
#define NIQ 100000
#define NHN 200000
#define CC 128
#define PDM 64
#define PHM 128
#define EHET 500000
#define EHOM 1000000
#define SCAN_CHUNK 2048

typedef __attribute__((ext_vector_type(8))) short bf16x8;
typedef __attribute__((ext_vector_type(4))) float f32x4;

__device__ inline unsigned short f2bf(float x) {
  union { float f; unsigned u; } c; c.f = x;
  unsigned r = c.u + 0x7FFF + ((c.u >> 16) & 1);
  return (unsigned short)(r >> 16);
}
__device__ inline float bflo(unsigned u) { union { unsigned u; float f; } c; c.u = u << 16; return c.f; }
__device__ inline float bfhi(unsigned u) { union { unsigned u; float f; } c; c.u = u & 0xffff0000u; return c.f; }

// ---------- fused degree counts: het (both dirs) + hom ----------
__global__ void k_setup(const int* __restrict__ eui_dst, const int* __restrict__ eiu_dst,
                        const int* __restrict__ ehom_dst,
                        int* __restrict__ cnt, int* __restrict__ cnt_hom) {
  int i = blockIdx.x * 256 + threadIdx.x;
  if (i < EHET) {
    atomicAdd(&cnt[NUQ + eui_dst[i]], 1);
  } else if (i < 2 * EHET) {
    atomicAdd(&cnt[eiu_dst[i - EHET]], 1);
  } else if (i < 2 * EHET + EHOM) {
    atomicAdd(&cnt_hom[ehom_dst[i - 2 * EHET]], 1);
  }
}

// ---------- fused 3-segment exclusive scan ----------
#define NB0 49
#define NB1 49
#define NB2 98
__global__ __launch_bounds__(256) void k_scan1f(const int* __restrict__ cnt, const int* __restrict__ cnt_hom,
                                                int* __restrict__ off_iu, int* __restrict__ off_ui,
                                                int* __restrict__ off_hom, int* __restrict__ blksum) {
  const int* in; int n; int* out; int* bs; int b;
  int blk = blockIdx.x;
  if (blk < NB0)            { in = cnt;       n = NUQ; out = off_iu;  bs = blksum;       b = blk; }
  else if (blk < NB0 + NB1) { in = cnt + NUQ; n = NIQ; out = off_ui;  bs = blksum + 256; b = blk - NB0; }
  else                      { in = cnt_hom;   n = NHN; out = off_hom; bs = blksum + 512; b = blk - NB0 - NB1; }
  __shared__ int sh[256];
  int t = threadIdx.x;
  int base = b * SCAN_CHUNK + t * 8;
  int v[8]; int s = 0;
#pragma unroll
  for (int i = 0; i < 8; ++i) {
    int x = (base + i < n) ? in[base + i] : 0;
    v[i] = s;
    s += x;
  }
  sh[t] = s; __syncthreads();
  for (int d = 1; d < 256; d <<= 1) {
    int x = (t >= d) ? sh[t - d] : 0;
    __syncthreads();
    sh[t] += x;
    __syncthreads();
  }
  int texcl = sh[t] - s;
#pragma unroll
  for (int i = 0; i < 8; ++i)
    if (base + i < n) out[base + i] = texcl + v[i];
  if (t == 255) bs[b] = sh[255];
}

__global__ void k_scan2f(const int* __restrict__ blksum, int* __restrict__ blkoff) {
  int seg = blockIdx.x;
  int nb = (seg == 2) ? NB2 : NB0;
  const int* bs = blksum + seg * 256;
  int* bo = blkoff + seg * 257;
  __shared__ int sh[256];
  int t = threadIdx.x;
  int x0 = (t < nb) ? bs[t] : 0;
  sh[t] = x0; __syncthreads();
  for (int d = 1; d < 256; d <<= 1) {
    int x = (t >= d) ? sh[t - d] : 0;
    __syncthreads();
    sh[t] += x;
    __syncthreads();
  }
  if (t < nb) bo[t] = sh[t] - x0;
  if (t == 0) bo[nb] = sh[255];
}

#define G0 392
#define G2 784
__global__ void k_scan3f(int* __restrict__ off_iu, int* __restrict__ off_ui, int* __restrict__ off_hom,
                         const int* __restrict__ blkoff) {
  int blk = blockIdx.x;
  int* off; int n; const int* bo; int nb; int b;
  if (blk < G0)           { off = off_iu;  n = NUQ; bo = blkoff;       nb = NB0; b = blk; }
  else if (blk < 2 * G0)  { off = off_ui;  n = NIQ; bo = blkoff + 257; nb = NB1; b = blk - G0; }
  else                    { off = off_hom; n = NHN; bo = blkoff + 514; nb = NB2; b = blk - 2 * G0; }
  int i = b * 256 + threadIdx.x;
  if (i < n) off[i] += bo[i >> 11];
  else if (i == n) off[n] = bo[nb];
}

// ---------- fused CSR fill via atomic cursor ----------
__global__ void k_fillf(const int* __restrict__ edge_ui, const int* __restrict__ edge_iu,
                        const int* __restrict__ edge_hom,
                        const int* __restrict__ off_ui, const int* __restrict__ off_iu,
                        const int* __restrict__ off_hom,
                        int* __restrict__ cur_i, int* __restrict__ cur_u, int* __restrict__ cur_h,
                        int* __restrict__ idx_ui, int* __restrict__ idx_iu, int* __restrict__ idx_hom) {
  int gid = blockIdx.x * 256 + threadIdx.x;
  if (gid < EHET) {
    int d = edge_ui[EHET + gid];
    int p = atomicAdd(&cur_i[d], 1);
    idx_ui[off_ui[d] + p] = edge_ui[gid];
  } else if (gid < 2 * EHET) {
    int e = gid - EHET;
    int d = edge_iu[EHET + e];
    int p = atomicAdd(&cur_u[d], 1);
    idx_iu[off_iu[d] + p] = edge_iu[e];
  } else if (gid < 2 * EHET + EHOM) {
    int e = gid - 2 * EHET;
    int d = edge_hom[EHOM + e];
    int p = atomicAdd(&cur_h[d], 1);
    idx_hom[off_hom[d] + p] = edge_hom[e];
  }
}

// ---------- PE -> bf16 copy ----------
__global__ __launch_bounds__(256) void k_pe2bf(const float* __restrict__ pe,
                                               unsigned* __restrict__ out) {
  int i = blockIdx.x * 256 + threadIdx.x;
  if (i < NHN * PDM / 2) {
    float2 v = *reinterpret_cast<const float2*>(&pe[(size_t)i * 2]);
    out[i] = (unsigned)f2bf(v.x) | ((unsigned)f2bf(v.y) << 16);
  }
}

// ---------- GIN neighborhood sum via CSR gather (16 lanes/node, unroll 4) ----------
__global__ __launch_bounds__(256) void k_aggcsr(const int* __restrict__ off, const int* __restrict__ idx,
                                                const unsigned short* __restrict__ pe_bf,
                                                float* __restrict__ agg) {
  int q = threadIdx.x >> 4, ql = threadIdx.x & 15;
  int n = blockIdx.x * 16 + q;
  int e0 = off[n], e1 = off[n + 1];
  float s0 = 0.f, s1 = 0.f, s2 = 0.f, s3 = 0.f;
  int e = e0;
  for (; e + 4 <= e1; e += 4) {
    int i0 = idx[e], i1 = idx[e + 1], i2 = idx[e + 2], i3 = idx[e + 3];
    uint2 a = *reinterpret_cast<const uint2*>(&pe_bf[(size_t)i0 * PDM + ql * 4]);
    uint2 b = *reinterpret_cast<const uint2*>(&pe_bf[(size_t)i1 * PDM + ql * 4]);
    uint2 c = *reinterpret_cast<const uint2*>(&pe_bf[(size_t)i2 * PDM + ql * 4]);
    uint2 d = *reinterpret_cast<const uint2*>(&pe_bf[(size_t)i3 * PDM + ql * 4]);
    s0 += bflo(a.x) + bflo(b.x) + bflo(c.x) + bflo(d.x);
    s1 += bfhi(a.x) + bfhi(b.x) + bfhi(c.x) + bfhi(d.x);
    s2 += bflo(a.y) + bflo(b.y) + bflo(c.y) + bflo(d.y);
    s3 += bfhi(a.y) + bfhi(b.y) + bfhi(c.y) + bfhi(d.y);
  }
  for (; e < e1; ++e) {
    uint2 a = *reinterpret_cast<const uint2*>(&pe_bf[(size_t)idx[e] * PDM + ql * 4]);
    s0 += bflo(a.x); s1 += bfhi(a.x); s2 += bflo(a.y); s3 += bfhi(a.y);
  }
  float4 o = { s0, s1, s2, s3 };
  *reinterpret_cast<float4*>(&agg[(size_t)n * PDM + ql * 4]) = o;
}

// ---------- single fused weight-prepack (14 segments) ----------
__device__ inline void pack_one(const float* W, int i, int NC, int kkBase, int KKtot,
                                unsigned short* out) {
  int k = i / NC, n = i % NC;
  int kk = kkBase + (k >> 5);
  int lane = (n & 15) + (((k >> 3) & 3) << 4);
  int j8 = k & 7;
  int o16 = ((n >> 4) * KKtot + kk) * 64 + lane;
  out[o16 * 8 + j8] = f2bf(W[i]);
}

__global__ __launch_bounds__(256) void k_packall(
    const float* __restrict__ siu_Wl, const float* __restrict__ siu_Wr,
    const float* __restrict__ sui_Wl, const float* __restrict__ sui_Wr,
    const float* __restrict__ pe_W, const float* __restrict__ phi_W1, const float* __restrict__ phi_W2,
    unsigned short* __restrict__ sageP, unsigned short* __restrict__ peP,
    unsigned short* __restrict__ g1P, unsigned short* __restrict__ g2P) {
  int seg = blockIdx.x / 96;
  int i = (blockIdx.x % 96) * 256 + threadIdx.x;
  int l = seg / 7, j = seg % 7;
  switch (j) {
    case 0: if (i < CC * 128) pack_one(siu_Wl + (size_t)l * CC * CC, i, 128, 0, 8, sageP + (size_t)(l * 2) * 32768); break;
    case 1: if (i < CC * 128) pack_one(siu_Wr + (size_t)l * CC * CC, i, 128, 4, 8, sageP + (size_t)(l * 2) * 32768); break;
    case 2: if (i < CC * 128) pack_one(sui_Wl + (size_t)l * CC * CC, i, 128, 0, 8, sageP + (size_t)(l * 2 + 1) * 32768); break;
    case 3: if (i < CC * 128) pack_one(sui_Wr + (size_t)l * CC * CC, i, 128, 4, 8, sageP + (size_t)(l * 2 + 1) * 32768); break;
    case 4: if (i < (CC + PDM) * 128) pack_one(pe_W + (size_t)l * (CC + PDM) * CC, i, 128, 0, 6, peP + (size_t)l * 24576); break;
    case 5: if (i < PDM * 128) pack_one(phi_W1 + (size_t)l * PDM * PHM, i, 128, 0, 2, g1P + (size_t)l * 8192); break;
    case 6: if (i < PHM * 64) pack_one(phi_W2 + (size_t)l * PHM * PDM, i, 64, 0, 4, g2P + (size_t)l * 8192); break;
  }
}

// ---------- fused GIN MLP via MFMA, BOTH layers: pel{0,1} = relu(h@W1+b1)@W2+b2 ----------
__global__ __launch_bounds__(256) void k_gin2(
    const float* __restrict__ pe, const float* __restrict__ agg,
    const unsigned short* __restrict__ g1P, const float* __restrict__ phi_b1,
    const unsigned short* __restrict__ g2P, const float* __restrict__ phi_b2,
    const float* __restrict__ eps_p,
    unsigned short* __restrict__ pel0, unsigned short* __restrict__ pel1) {
  __shared__ __align__(16) char Ah[32 * 128];
  __shared__ __align__(16) char Hh[32 * 256];
  int t = threadIdx.x, wave = t >> 6, lane = t & 63;
  int row0 = blockIdx.x * 32;
  int rt = wave & 1, ctb = (wave >> 1) * 4;
  int arow = rt * 16 + (lane & 15);
  int axor = arow & 7;
#pragma unroll
  for (int l = 0; l < 2; ++l) {
    const unsigned short* B1p = g1P + (size_t)l * 8192;
    const unsigned short* B2p = g2P + (size_t)l * 8192;
    const float* b1 = phi_b1 + (size_t)l * PHM;
    const float* b2 = phi_b2 + (size_t)l * PDM;
    unsigned short* pel = l ? pel1 : pel0;
    float e1 = 1.0f + eps_p[l];
    for (int i = t; i < 32 * 32; i += 256) {
      int r = i >> 5, cp = i & 31;
      float2 p2 = *reinterpret_cast<const float2*>(&pe[(size_t)(row0 + r) * PDM + cp * 2]);
      float2 a2 = *reinterpret_cast<const float2*>(&agg[(size_t)(row0 + r) * PDM + cp * 2]);
      unsigned pv = (unsigned)f2bf(e1 * p2.x + a2.x) | ((unsigned)f2bf(e1 * p2.y + a2.y) << 16);
      int chunk = (cp >> 2) ^ (r & 7);
      *reinterpret_cast<unsigned*>(Ah + r * 128 + chunk * 16 + (cp & 3) * 4) = pv;
    }
    __syncthreads();
    // GEMM1: [32x64] @ [64x128]
    {
      f32x4 acc0 = {0.f, 0.f, 0.f, 0.f}, acc1 = acc0, acc2 = acc0, acc3 = acc0;
      const char* abase = Ah + arow * 128;
      const bf16x8* bv = reinterpret_cast<const bf16x8*>(B1p);
      for (int kk = 0; kk < 2; ++kk) {
        bf16x8 a = *reinterpret_cast<const bf16x8*>(abase + (((kk * 4 + (lane >> 4)) ^ axor) * 16));
        const bf16x8* bp = bv + (size_t)kk * 64 + lane;
        acc0 = __builtin_amdgcn_mfma_f32_16x16x32_bf16(a, bp[(size_t)(ctb + 0) * 2 * 64], acc0, 0, 0, 0);
        acc1 = __builtin_amdgcn_mfma_f32_16x16x32_bf16(a, bp[(size_t)(ctb + 1) * 2 * 64], acc1, 0, 0, 0);
        acc2 = __builtin_amdgcn_mfma_f32_16x16x32_bf16(a, bp[(size_t)(ctb + 2) * 2 * 64], acc2, 0, 0, 0);
        acc3 = __builtin_amdgcn_mfma_f32_16x16x32_bf16(a, bp[(size_t)(ctb + 3) * 2 * 64], acc3, 0, 0, 0);
      }
      int prow = rt * 16 + ((lane >> 4) << 2);
      int c0 = ctb * 16 + (lane & 15);
      float bb0 = b1[c0], bb1 = b1[c0 + 16], bb2 = b1[c0 + 32], bb3 = b1[c0 + 48];
      int j2 = (c0 & 7) * 2, cb = c0 >> 3;
#pragma unroll
      for (int q = 0; q < 4; ++q) {
        int rw = prow + q, rx = rw & 7;
        char* hb = Hh + rw * 256;
        *reinterpret_cast<unsigned short*>(hb + (((cb + 0) ^ rx) * 16) + j2) = f2bf(fmaxf(acc0[q] + bb0, 0.f));
        *reinterpret_cast<unsigned short*>(hb + (((cb + 2) ^ rx) * 16) + j2) = f2bf(fmaxf(acc1[q] + bb1, 0.f));
        *reinterpret_cast<unsigned short*>(hb + (((cb + 4) ^ rx) * 16) + j2) = f2bf(fmaxf(acc2[q] + bb2, 0.f));
        *reinterpret_cast<unsigned short*>(hb + (((cb + 6) ^ rx) * 16) + j2) = f2bf(fmaxf(acc3[q] + bb3, 0.f));
      }
    }
    __syncthreads();
    // GEMM2: [32x128] @ [128x64]
    {
      int ct2 = (wave >> 1) * 2;
      f32x4 d0 = {0.f, 0.f, 0.f, 0.f}, d1 = d0;
      const char* hbase = Hh + arow * 256;
      const bf16x8* bv = reinterpret_cast<const bf16x8*>(B2p);
      for (int kk = 0; kk < 4; ++kk) {
        bf16x8 a = *reinterpret_cast<const bf16x8*>(hbase + (((kk * 4 + (lane >> 4)) ^ axor) * 16));
        const bf16x8* bp = bv + (size_t)kk * 64 + lane;
        d0 = __builtin_amdgcn_mfma_f32_16x16x32_bf16(a, bp[(size_t)(ct2 + 0) * 4 * 64], d0, 0, 0, 0);
        d1 = __builtin_amdgcn_mfma_f32_16x16x32_bf16(a, bp[(size_t)(ct2 + 1) * 4 * 64], d1, 0, 0, 0);
      }
      int prow0 = row0 + rt * 16 + ((lane >> 4) << 2);
      int c0 = ct2 * 16 + (lane & 15);
      float bb0 = b2[c0], bb1 = b2[c0 + 16];
#pragma unroll
      for (int q = 0; q < 4; ++q) {
        pel[(size_t)(prow0 + q) * PDM + c0] = f2bf(d0[q] + bb0);
        pel[(size_t)(prow0 + q) * PDM + c0 + 16] = f2bf(d1[q] + bb1);
      }
    }
    __syncthreads();
  }
}

// ---------- peproj (layer 0 only): y0 = concat(x, pel0) @ pe_W + pe_b ----------
__global__ __launch_bounds__(256) void k_peproj_mfma(
    const float* __restrict__ xu, const float* __restrict__ xi,
    const unsigned short* __restrict__ pel,
    const unsigned short* __restrict__ Bp, const float* __restrict__ bias,
    unsigned short* __restrict__ y_bf) {
  __shared__ __align__(16) char Abuf[32 * 384];
  int t = threadIdx.x, wave = t >> 6, lane = t & 63;
  int row0 = blockIdx.x * 32;
  const float* xs = (row0 < NUQ) ? xu : xi;
  int rbase = (row0 < NUQ) ? row0 : row0 - NUQ;
  for (int i = t; i < 32 * 64; i += 256) {
    int r = i >> 6, cp = i & 63;
    float2 v = *reinterpret_cast<const float2*>(&xs[(size_t)(rbase + r) * CC + cp * 2]);
    unsigned pv = (unsigned)f2bf(v.x) | ((unsigned)f2bf(v.y) << 16);
    int chunk = (cp >> 2) ^ (r & 7);
    *reinterpret_cast<unsigned*>(Abuf + r * 384 + chunk * 16 + (cp & 3) * 4) = pv;
  }
  for (int i = t; i < 32 * 32; i += 256) {
    int r = i >> 5, cp = i & 31;
    unsigned pv = *reinterpret_cast<const unsigned*>(&pel[(size_t)(row0 + r) * PDM + cp * 2]);
    int chunk = (16 + (cp >> 2)) ^ (r & 7);
    *reinterpret_cast<unsigned*>(Abuf + r * 384 + chunk * 16 + (cp & 3) * 4) = pv;
  }
  __syncthreads();
  int rt = wave & 1, ctb = (wave >> 1) * 4;
  f32x4 acc0 = {0.f, 0.f, 0.f, 0.f}, acc1 = acc0, acc2 = acc0, acc3 = acc0;
  int arow = rt * 16 + (lane & 15);
  const char* abase = Abuf + arow * 384;
  int axor = arow & 7;
  const bf16x8* bp0 = reinterpret_cast<const bf16x8*>(Bp);
  for (int kk = 0; kk < 6; ++kk) {
    bf16x8 a = *reinterpret_cast<const bf16x8*>(abase + (((kk * 4 + (lane >> 4)) ^ axor) * 16));
    const bf16x8* bp = bp0 + (size_t)kk * 64 + lane;
    acc0 = __builtin_amdgcn_mfma_f32_16x16x32_bf16(a, bp[(size_t)(ctb + 0) * 6 * 64], acc0, 0, 0, 0);
    acc1 = __builtin_amdgcn_mfma_f32_16x16x32_bf16(a, bp[(size_t)(ctb + 1) * 6 * 64], acc1, 0, 0, 0);
    acc2 = __builtin_amdgcn_mfma_f32_16x16x32_bf16(a, bp[(size_t)(ctb + 2) * 6 * 64], acc2, 0, 0, 0);
    acc3 = __builtin_amdgcn_mfma_f32_16x16x32_bf16(a, bp[(size_t)(ctb + 3) * 6 * 64], acc3, 0, 0, 0);
  }
  int prow0 = row0 + rt * 16 + ((lane >> 4) << 2);
  int c0 = ctb * 16 + (lane & 15);
  float b0 = bias[c0], b1 = bias[c0 + 16], b2 = bias[c0 + 32], b3 = bias[c0 + 48];
#pragma unroll
  for (int q = 0; q < 4; ++q) {
    size_t rb = (size_t)(prow0 + q) * CC;
    y_bf[rb + c0]      = f2bf(acc0[q] + b0);
    y_bf[rb + c0 + 16] = f2bf(acc1[q] + b1);
    y_bf[rb + c0 + 32] = f2bf(acc2[q] + b2);
    y_bf[rb + c0 + 48] = f2bf(acc3[q] + b3);
  }
}

// ---------- fused: CSR mean-gather + dual GEMM (K=256) + LN + ReLU
//            [+ optional fused next-layer peproj -> y_out bf16] ----------
template <bool FUSE>
__global__ __launch_bounds__(256) void k_sage_mfma(
    const unsigned short* __restrict__ y_bf,
    const int* __restrict__ offU, const int* __restrict__ idxU,
    const int* __restrict__ offI, const int* __restrict__ idxI,
    const int* __restrict__ cnt,
    const unsigned short* __restrict__ BpU, const unsigned short* __restrict__ BpI,
    const float* __restrict__ blU, const float* __restrict__ blI,
    const float* __restrict__ gU, const float* __restrict__ beU,
    const float* __restrict__ gI, const float* __restrict__ beI,
    const unsigned short* __restrict__ pel2, const unsigned short* __restrict__ Bp2,
    const float* __restrict__ bias2,
    unsigned short* __restrict__ y_out, float* __restrict__ xh) {
  __shared__ __align__(16) char U[32 * 132 * 4 + 32 * 8];
  char* Abuf = U;
  float (*preLN)[132] = reinterpret_cast<float (*)[132]>(U);
  float (*stat)[2] = reinterpret_cast<float (*)[2]>(U + 32 * 132 * 4);
  int t = threadIdx.x, wave = t >> 6, lane = t & 63;
  int row0 = blockIdx.x * 32;
  bool isU = row0 < NUQ;
  const int* off = isU ? offU : offI;
  const int* idx = isU ? idxU : idxI;
  int dBase = isU ? 0 : NUQ;
  int sBase = isU ? NUQ : 0;
  const unsigned short* Bp = isU ? BpU : BpI;
  const float* bl = isU ? blU : blI;
  const float* g  = isU ? gU : gI;
  const float* be = isU ? beU : beI;

  // stage: wave owns 8 rows, 4 rows concurrently (16 lanes x uint4), edge unroll 4
  int qg = lane >> 4, ql = lane & 15;
  for (int pr = 0; pr < 2; ++pr) {
    int r = wave * 8 + pr * 4 + qg;
    int d = row0 + r;
    int e0 = off[d - dBase], e1 = off[d - dBase + 1];
    float s0 = 0.f, s1 = 0.f, s2 = 0.f, s3 = 0.f, s4 = 0.f, s5 = 0.f, s6 = 0.f, s7 = 0.f;
    int e = e0;
    for (; e + 4 <= e1; e += 4) {
      int i0 = idx[e], i1 = idx[e + 1], i2 = idx[e + 2], i3 = idx[e + 3];
      uint4 a = *reinterpret_cast<const uint4*>(&y_bf[(size_t)(sBase + i0) * CC + ql * 8]);
      uint4 b = *reinterpret_cast<const uint4*>(&y_bf[(size_t)(sBase + i1) * CC + ql * 8]);
      uint4 c = *reinterpret_cast<const uint4*>(&y_bf[(size_t)(sBase + i2) * CC + ql * 8]);
      uint4 dv = *reinterpret_cast<const uint4*>(&y_bf[(size_t)(sBase + i3) * CC + ql * 8]);
      s0 += bflo(a.x) + bflo(b.x) + bflo(c.x) + bflo(dv.x);
      s1 += bfhi(a.x) + bfhi(b.x) + bfhi(c.x) + bfhi(dv.x);
      s2 += bflo(a.y) + bflo(b.y) + bflo(c.y) + bflo(dv.y);
      s3 += bfhi(a.y) + bfhi(b.y) + bfhi(c.y) + bfhi(dv.y);
      s4 += bflo(a.z) + bflo(b.z) + bflo(c.z) + bflo(dv.z);
      s5 += bfhi(a.z) + bfhi(b.z) + bfhi(c.z) + bfhi(dv.z);
      s6 += bflo(a.w) + bflo(b.w) + bflo(c.w) + bflo(dv.w);
      s7 += bfhi(a.w) + bfhi(b.w) + bfhi(c.w) + bfhi(dv.w);
    }
    for (; e < e1; ++e) {
      uint4 a = *reinterpret_cast<const uint4*>(&y_bf[(size_t)(sBase + idx[e]) * CC + ql * 8]);
      s0 += bflo(a.x); s1 += bfhi(a.x); s2 += bflo(a.y); s3 += bfhi(a.y);
      s4 += bflo(a.z); s5 += bfhi(a.z); s6 += bflo(a.w); s7 += bfhi(a.w);
    }
    float inv = 1.0f / fmaxf((float)cnt[d], 1.0f);
    uint4 pm;
    pm.x = (unsigned)f2bf(s0 * inv) | ((unsigned)f2bf(s1 * inv) << 16);
    pm.y = (unsigned)f2bf(s2 * inv) | ((unsigned)f2bf(s3 * inv) << 16);
    pm.z = (unsigned)f2bf(s4 * inv) | ((unsigned)f2bf(s5 * inv) << 16);
    pm.w = (unsigned)f2bf(s6 * inv) | ((unsigned)f2bf(s7 * inv) << 16);
    int ch = ql ^ (r & 7);
    *reinterpret_cast<uint4*>(Abuf + r * 512 + ch * 16) = pm;
    uint4 pv = *reinterpret_cast<const uint4*>(&y_bf[(size_t)(row0 + r) * CC + ql * 8]);
    *reinterpret_cast<uint4*>(Abuf + r * 512 + (16 + ch) * 16) = pv;
  }
  __syncthreads();
  // MFMA: K=256 over [mean | y]
  int rt = wave & 1, ctb = (wave >> 1) * 4;
  int arow = rt * 16 + (lane & 15);
  int axor = arow & 7;
  {
    f32x4 acc0 = {0.f, 0.f, 0.f, 0.f}, acc1 = acc0, acc2 = acc0, acc3 = acc0;
    const char* abase = Abuf + arow * 512;
    const bf16x8* bp0 = reinterpret_cast<const bf16x8*>(Bp);
    for (int kk = 0; kk < 8; ++kk) {
      bf16x8 a = *reinterpret_cast<const bf16x8*>(abase + (((kk * 4 + (lane >> 4)) ^ axor) * 16));
      const bf16x8* bp = bp0 + (size_t)kk * 64 + lane;
      acc0 = __builtin_amdgcn_mfma_f32_16x16x32_bf16(a, bp[(size_t)(ctb + 0) * 8 * 64], acc0, 0, 0, 0);
      acc1 = __builtin_amdgcn_mfma_f32_16x16x32_bf16(a, bp[(size_t)(ctb + 1) * 8 * 64], acc1, 0, 0, 0);
      acc2 = __builtin_amdgcn_mfma_f32_16x16x32_bf16(a, bp[(size_t)(ctb + 2) * 8 * 64], acc2, 0, 0, 0);
      acc3 = __builtin_amdgcn_mfma_f32_16x16x32_bf16(a, bp[(size_t)(ctb + 3) * 8 * 64], acc3, 0, 0, 0);
    }
    __syncthreads();   // Abuf dead; preLN aliases it
    int prow = rt * 16 + ((lane >> 4) << 2);
    int c0 = ctb * 16 + (lane & 15);
    float b0 = bl[c0], b1 = bl[c0 + 16], b2 = bl[c0 + 32], b3 = bl[c0 + 48];
#pragma unroll
    for (int q = 0; q < 4; ++q) {
      preLN[prow + q][c0]      = acc0[q] + b0;
      preLN[prow + q][c0 + 16] = acc1[q] + b1;
      preLN[prow + q][c0 + 32] = acc2[q] + b2;
      preLN[prow + q][c0 + 48] = acc3[q] + b3;
    }
  }
  __syncthreads();
  {
    int rr = t >> 3, j = t & 7;
    float s = 0.f, sq = 0.f;
#pragma unroll
    for (int i = 0; i < 16; ++i) { float v = preLN[rr][j + 8 * i]; s += v; sq += v * v; }
    s += __shfl_xor(s, 1); sq += __shfl_xor(sq, 1);
    s += __shfl_xor(s, 2); sq += __shfl_xor(sq, 2);
    s += __shfl_xor(s, 4); sq += __shfl_xor(sq, 4);
    if (j == 0) {
      float mu = s * (1.0f / CC);
      float var = sq * (1.0f / CC) - mu * mu;
      stat[rr][0] = mu;
      stat[rr][1] = rsqrtf(var + 1e-5f);
    }
  }
  __syncthreads();
  if (!FUSE) {
    for (int i = t; i < 32 * CC; i += 256) {
      int r = i >> 7, c = i & 127;
      float v = (preLN[r][c] - stat[r][0]) * stat[r][1] * g[c] + be[c];
      xh[(size_t)(row0 + r) * CC + c] = fmaxf(v, 0.f);
    }
  } else {
    // x = relu(LN(...)) into registers (column c fixed per thread, 16 rows)
    float vx[16];
    int cx = t & 127, rb0 = t >> 7;
    float gc = g[cx], bec = be[cx];
#pragma unroll
    for (int k = 0; k < 16; ++k) {
      int r = rb0 + 2 * k;
      float v = (preLN[r][cx] - stat[r][0]) * stat[r][1] * gc + bec;
      vx[k] = fmaxf(v, 0.f);
    }
    __syncthreads();   // all preLN reads done; Abuf reusable
    // write x frags (chunks 0..15) + pel2 frags (chunks 16..23)
    {
      int chunkx = cx >> 3;
      int bofs = (cx & 7) * 2;
#pragma unroll
      for (int k = 0; k < 16; ++k) {
        int r = rb0 + 2 * k;
        *reinterpret_cast<unsigned short*>(Abuf + r * 512 + ((chunkx ^ (r & 7)) * 16) + bofs) = f2bf(vx[k]);
      }
    }
    for (int i = t; i < 32 * 32; i += 256) {
      int r = i >> 5, cp = i & 31;
      unsigned pv = *reinterpret_cast<const unsigned*>(&pel2[(size_t)(row0 + r) * PDM + cp * 2]);
      int chunk = 16 + ((cp >> 2) ^ (r & 7));
      *reinterpret_cast<unsigned*>(Abuf + r * 512 + chunk * 16 + (cp & 3) * 4) = pv;
    }
    __syncthreads();
    // K=192 MFMA with next layer's pe_W
    f32x4 acc0 = {0.f, 0.f, 0.f, 0.f}, acc1 = acc0, acc2 = acc0, acc3 = acc0;
    const char* abase = Abuf + arow * 512;
    const bf16x8* bp0 = reinterpret_cast<const bf16x8*>(Bp2);
    for (int kk = 0; kk < 6; ++kk) {
      bf16x8 a = *reinterpret_cast<const bf16x8*>(abase + (((kk * 4 + (lane >> 4)) ^ axor) * 16));
      const bf16x8* bp = bp0 + (size_t)kk * 64 + lane;
      acc0 = __builtin_amdgcn_mfma_f32_16x16x32_bf16(a, bp[(size_t)(ctb + 0) * 6 * 64], acc0, 0, 0, 0);
      acc1 = __builtin_amdgcn_mfma_f32_16x16x32_bf16(a, bp[(size_t)(ctb + 1) * 6 * 64], acc1, 0, 0, 0);
      acc2 = __builtin_amdgcn_mfma_f32_16x16x32_bf16(a, bp[(size_t)(ctb + 2) * 6 * 64], acc2, 0, 0, 0);
      acc3 = __builtin_amdgcn_mfma_f32_16x16x32_bf16(a, bp[(size_t)(ctb + 3) * 6 * 64], acc3, 0, 0, 0);
    }
    int prow0 = row0 + rt * 16 + ((lane >> 4) << 2);
    int c0 = ctb * 16 + (lane & 15);
    float b0 = bias2[c0], b1 = bias2[c0 + 16], b2 = bias2[c0 + 32], b3 = bias2[c0 + 48];
#pragma unroll
    for (int q = 0; q < 4; ++q) {
      size_t rb = (size_t)(prow0 + q) * CC;
      y_out[rb + c0]      = f2bf(acc0[q] + b0);
      y_out[rb + c0 + 16] = f2bf(acc1[q] + b1);
      y_out[rb + c0 + 32] = f2bf(acc2[q] + b2);
      y_out[rb + c0 + 48] = f2bf(acc3[q] + b3);
    }
  }
}

extern "C" void kernel_launch(void* const* d_in, const int* in_sizes, int n_in,
                              void* d_out, int out_size, void* d_ws, size_t ws_size,
                              hipStream_t stream) {
  const float* x_user = (const float*)d_in[0];
  const float* x_item = (const float*)d_in[1];
  const float* PE     = (const float*)d_in[2];
  const float* sui_Wl = (const float*)d_in[3];
  const float* sui_bl = (const float*)d_in[4];
  const float* sui_Wr = (const float*)d_in[5];
  const float* siu_Wl = (const float*)d_in[6];
  const float* siu_bl = (const float*)d_in[7];
  const float* siu_Wr = (const float*)d_in[8];
  const float* lnu_g  = (const float*)d_in[9];
  const float* lnu_b  = (const float*)d_in[10];
  const float* lni_g  = (const float*)d_in[11];
  const float* lni_b  = (const float*)d_in[12];
  const float* phi_eps = (const float*)d_in[13];
  const float* phi_W1  = (const float*)d_in[14];
  const float* phi_b1  = (const float*)d_in[15];
  const float* phi_W2  = (const float*)d_in[16];
  const float* phi_b2  = (const float*)d_in[17];
  const float* pe_W    = (const float*)d_in[18];
  const float* pe_b    = (const float*)d_in[19];
  const int* edge_ui   = (const int*)d_in[20];
  const int* edge_iu   = (const int*)d_in[21];
  const int* edge_hom  = (const int*)d_in[22];

  float* xh = (float*)d_out;                                    // [NH][C] f32 (final)
  float* agg = (float*)d_ws;                                    // [NH][PD] f32
  unsigned short* y0    = (unsigned short*)(agg + (size_t)NHN * PDM);  // [NH][C]
  unsigned short* y1    = y0 + (size_t)NHN * CC;                // [NH][C]
  unsigned short* pel0  = y1 + (size_t)NHN * CC;                // [NH][PD]
  unsigned short* pel1  = pel0 + (size_t)NHN * PDM;             // [NH][PD]
  unsigned short* pe_bf = pel1 + (size_t)NHN * PDM;             // [NH][PD]
  int* ip = (int*)(pe_bf + (size_t)NHN * PDM);
  // contiguous zero-region (single memset): cnt, cnt_hom, cur_u, cur_i, cur_h
  int* cnt      = ip;             ip += NHN;
  int* cnt_hom  = ip;             ip += NHN;
  int* cur_u    = ip;             ip += NUQ;
  int* cur_i    = ip;             ip += NIQ;
  int* cur_h    = ip;             ip += NHN;
  int* off_iu   = ip;             ip += NUQ + 1;
  int* off_ui   = ip;             ip += NIQ + 1;
  int* off_hom  = ip;             ip += NHN + 1;
  int* idx_ui   = ip;             ip += EHET;
  int* idx_iu   = ip;             ip += EHET;
  int* idx_hom  = ip;             ip += EHOM;
  int* blksum   = ip;             ip += 3 * 256;
  int* blkoff   = ip;             ip += 3 * 257;
  unsigned short* packs = (unsigned short*)((((size_t)(ip)) + 15) & ~(size_t)15);
  unsigned short* sageP = packs;                    // [L][2 types] x 32768
  unsigned short* peP   = sageP + 4 * 32768;        // [L] x 24576
  unsigned short* g1P   = peP + 2 * 24576;          // [L] x 8192
  unsigned short* g2P   = g1P + 2 * 8192;           // [L] x 8192

  (void)hipMemsetAsync(cnt, 0, (size_t)(2 * NHN + NUQ + NIQ + NHN) * sizeof(int), stream);

  k_setup<<<(2 * EHET + EHOM + 255) / 256, 256, 0, stream>>>(
      edge_ui + EHET, edge_iu + EHET, edge_hom + EHOM, cnt, cnt_hom);
  k_pe2bf<<<(NHN * PDM / 2 + 255) / 256, 256, 0, stream>>>(PE, (unsigned*)pe_bf);

  k_scan1f<<<NB0 + NB1 + NB2, 256, 0, stream>>>(cnt, cnt_hom, off_iu, off_ui, off_hom, blksum);
  k_scan2f<<<3, 256, 0, stream>>>(blksum, blkoff);
  k_scan3f<<<2 * G0 + G2, 256, 0, stream>>>(off_iu, off_ui, off_hom, blkoff);
  k_fillf<<<(2 * EHET + EHOM + 255) / 256, 256, 0, stream>>>(
      edge_ui, edge_iu, edge_hom, off_ui, off_iu, off_hom,
      cur_i, cur_u, cur_h, idx_ui, idx_iu, idx_hom);

  k_aggcsr<<<NHN / 16, 256, 0, stream>>>(off_hom, idx_hom, pe_bf, agg);
  k_packall<<<14 * 96, 256, 0, stream>>>(siu_Wl, siu_Wr, sui_Wl, sui_Wr, pe_W, phi_W1, phi_W2,
                                         sageP, peP, g1P, g2P);

  k_gin2<<<NHN / 32, 256, 0, stream>>>(PE, agg, g1P, phi_b1, g2P, phi_b2, phi_eps, pel0, pel1);
  k_peproj_mfma<<<NHN / 32, 256, 0, stream>>>(x_user, x_item, pel0, peP, pe_b, y0);

  // layer 0: SAGE + LN + ReLU + fused layer-1 peproj -> y1 (no xh round-trip)
  k_sage_mfma<true><<<NHN / 32, 256, 0, stream>>>(y0,
      off_iu, idx_iu, off_ui, idx_ui, cnt,
      sageP + (size_t)0 * 32768, sageP + (size_t)1 * 32768,
      siu_bl, sui_bl, lnu_g, lnu_b, lni_g, lni_b,
      pel1, peP + 24576, pe_b + CC, y1, nullptr);

  // layer 1: SAGE + LN + ReLU -> xh (final f32 output)
  k_sage_mfma<false><<<NHN / 32, 256, 0, stream>>>(y1,
      off_iu, idx_iu, off_ui, idx_ui, cnt,
      sageP + (size_t)2 * 32768, sageP + (size_t)3 * 32768,
      siu_bl + CC, sui_bl + CC,
      lnu_g + CC, lnu_b + CC, lni_g + CC, lni_b + CC,
      nullptr, nullptr, nullptr, nullptr, xh);
}